// Round 6
// baseline (195.712 us; speedup 1.0000x reference)
//
#include <hip/hip_runtime.h>

// AdaptiveSpectrumLayer: B=128, H=T=512, F=16, NF=257
// v13: - k_spec un-fused back to k_fftg + k_new (k_spec was 42 µs at 1 block/CU,
//        latency-bound VALU epilogue; k_new at 2056 blocks = 8/CU hides it).
//      - k_gemm: v12 streaming loop + XCD-aware block decode (xcd=bid&7 owns
//        4 sp-slices -> B working set 1.3 MB L2-resident; kills the L3-latency
//        bound 337 MB B re-read path that made v11/v12 gemm ~40 µs).
//      - prep / recong unchanged (SPK=32).

#define NF_ 257
#define NKB 514          // K blocks of 32: NF_*64/32
#define FRAGS 263168     // NKB*512 shorts: stride between m/n blocks in frag space
#define SPK 32
#define SORTHO 0.04419417382f   // 1/sqrt(512)

typedef __attribute__((ext_vector_type(8))) short short8;
typedef __attribute__((ext_vector_type(4))) float floatx4;

__device__ __forceinline__ unsigned int f2bf(float x) {
  union { float f; unsigned int u; } v; v.f = x;
  return (v.u + 0x7FFFu + ((v.u >> 16) & 1u)) >> 16;
}
__device__ __forceinline__ float bf2f(unsigned int u16) {
  union { unsigned int u; float f; } v; v.u = u16 << 16;
  return v.f;
}

// ---------- K_prep: fused {csd | wgt | tw | itw} by blockIdx range.
// blocks [0,128): csd; [128,2698): wgt; [2698,2834): tw; [2834,2970): itw.
__global__ __launch_bounds__(256) void k_prep(const float* __restrict__ x,
                                              const float* __restrict__ Wg,
                                              float* __restrict__ csd,
                                              unsigned short* __restrict__ Bf,
                                              unsigned short* __restrict__ TWf,
                                              unsigned short* __restrict__ ITWf) {
  __shared__ float sl[768];
  __shared__ float ac[257];
  __shared__ float red[4];
  const int tid = threadIdx.x;
  const int blk = blockIdx.x;

  if (blk < 128) {
    // ---- csd[b][k] = (1/(256*sqrt(512))) * DFT_t( autocorr(s)[t-255] )
    const int bb = blk;
    for (int t = tid; t < 768; t += 256) {
      float v = 0.f;
      if (t < 512) {
        const float4* xp = (const float4*)(x + (bb * 512 + t) * 16);
        float4 a = xp[0], b = xp[1], c = xp[2], d = xp[3];
        v = a.x + a.y + a.z + a.w + b.x + b.y + b.z + b.w +
            c.x + c.y + c.z + c.w + d.x + d.y + d.z + d.w;
      }
      sl[t] = v;
    }
    __syncthreads();
    {
      float a0 = 0.f, a1 = 0.f, a2 = 0.f, a3 = 0.f;
      for (int tau = 0; tau < 512; tau += 4) {
        float4 u = *(const float4*)&sl[tau];
        a0 = fmaf(u.x, sl[tau + tid], a0);
        a1 = fmaf(u.y, sl[tau + tid + 1], a1);
        a2 = fmaf(u.z, sl[tau + tid + 2], a2);
        a3 = fmaf(u.w, sl[tau + tid + 3], a3);
      }
      ac[tid] = (a0 + a1) + (a2 + a3);
    }
    {
      float p = sl[tid] * sl[tid + 256];
#pragma unroll
      for (int off = 32; off; off >>= 1) p += __shfl_down(p, off);
      if ((tid & 63) == 0) red[tid >> 6] = p;
    }
    __syncthreads();
    if (tid == 0) ac[256] = red[0] + red[1] + red[2] + red[3];
    __syncthreads();
    const float S1 = SORTHO / 256.f;
    const int k = tid;            // 0..255; k=256 via exact alternating chain
    float sth, cth;
    __sincosf((float)k * 0.01227184630f, &sth, &cth);
    float c = 1.f, s = 0.f, re = 0.f, im = 0.f;
    float re256 = 0.f, sg = 1.f;
    for (int t = 0; t < 512; ++t) {
      int d = t - 255;
      float ov = ac[d < 0 ? -d : d];
      re = fmaf(ov, c, re);
      im = fmaf(-ov, s, im);
      re256 = fmaf(ov, sg, re256);
      sg = -sg;
      float nc = fmaf(c, cth, -s * sth);
      s = fmaf(s, cth, c * sth);
      c = nc;
    }
    *(float2*)(csd + (bb * NF_ + k) * 2) = make_float2(re * S1, im * S1);
    if (tid == 0)
      *(float2*)(csd + (bb * NF_ + 256) * 2) = make_float2(re256 * S1, 0.f);
    return;
  }

  if (blk < 2698) {
    // ---- W_gate (16448 x 257 f32) -> Bfrag bf16 fragment-major.
    const int slot = (blk - 128) * 256 + tid;          // < 657920
    const int nblk = slot / 32896;                     // 514*64
    const int rem = slot - nblk * 32896;
    const int kb = rem >> 6, lane = rem & 63;
    const int n = nblk * 16 + (lane & 15);
    const int k0 = kb * 32 + (lane >> 4) * 8;
    unsigned int w[4];
#pragma unroll
    for (int jp = 0; jp < 4; ++jp) {
      float v0 = (n < NF_) ? Wg[(k0 + jp * 2) * NF_ + n] : 0.f;
      float v1 = (n < NF_) ? Wg[(k0 + jp * 2 + 1) * NF_ + n] : 0.f;
      w[jp] = f2bf(v0) | (f2bf(v1) << 16);
    }
    *(uint4*)(Bf + (size_t)slot * 8) = make_uint4(w[0], w[1], w[2], w[3]);
    return;
  }

  if (blk < 2834) {
    // ---- rfft twiddle table, fragment-major, S folded.
    const int slot = (blk - 2698) * 256 + tid;   // < 34816
    const int tile = slot >> 10, rem = slot & 1023;
    const int ks = rem >> 6, quad = (rem >> 4) & 3, l15 = rem & 15;
    const int grow = tile * 16 + l15;
    unsigned int pk[4];
#pragma unroll
    for (int jp = 0; jp < 4; ++jp) {
      float v0 = 0.f, v1 = 0.f;
      if (grow < 514) {
        const int k = grow >> 1;
        const int t0 = ks * 32 + quad * 8 + jp * 2;
        float s0, c0, s1, c1;
        __sincosf((float)((k * t0) & 511) * 0.01227184630f, &s0, &c0);
        __sincosf((float)((k * (t0 + 1)) & 511) * 0.01227184630f, &s1, &c1);
        v0 = (grow & 1) ? -s0 * SORTHO : c0 * SORTHO;
        v1 = (grow & 1) ? -s1 * SORTHO : c1 * SORTHO;
      }
      pk[jp] = f2bf(v0) | (f2bf(v1) << 16);
    }
    *(uint4*)(TWf + slot * 8) = make_uint4(pk[0], pk[1], pk[2], pk[3]);
    return;
  }

  {
    // ---- irfft twiddle table, fragment-major, S + Hermitian folded.
    const int slot = (blk - 2834) * 256 + tid;   // < 34816
    const int tile = slot / 1088, rem = slot % 1088;
    const int ks = rem >> 6, sub = rem & 63;
    const int quad = sub >> 4, l15 = sub & 15;
    const int t = tile * 16 + l15;
    unsigned int pk[4];
#pragma unroll
    for (int jp = 0; jp < 4; ++jp) {
      float v0 = 0.f, v1 = 0.f;
#pragma unroll
      for (int h = 0; h < 2; ++h) {
        const int kidx = ks * 32 + quad * 8 + jp * 2 + h;
        float v = 0.f;
        if (kidx < 514) {
          const int k = kidx >> 1;
          const float hw = (k == 0 || k == 256) ? SORTHO : 2.f * SORTHO;
          float s, c;
          __sincosf((float)((k * t) & 511) * 0.01227184630f, &s, &c);
          v = (kidx & 1) ? -s * hw : c * hw;
        }
        if (h == 0) v0 = v; else v1 = v;
      }
      pk[jp] = f2bf(v0) | (f2bf(v1) << 16);
    }
    *(uint4*)(ITWf + slot * 8) = make_uint4(pk[0], pk[1], pk[2], pk[3]);
  }
}

// ---------- K3: rfft GEMM: fftc = TWf x X^T + csd. grid (2,128) x 512 thr.
__global__ __launch_bounds__(512) void k_fftg(const float* __restrict__ x,
                                              const unsigned short* __restrict__ TWf,
                                              const float* __restrict__ csd,
                                              float* __restrict__ fftc) {
  __shared__ __align__(16) unsigned short Xs[16 * 512];
  const int tid = threadIdx.x, mh = blockIdx.x, bb = blockIdx.y;
#pragma unroll
  for (int it = 0; it < 16; ++it) {
    int e = it * 512 + tid;
    int f = e & 15, t = e >> 4;
    float val = x[(bb * 512 + t) * 16 + f];
    Xs[f * 512 + (((t >> 3) ^ (f & 7)) * 8) + (t & 7)] = (unsigned short)f2bf(val);
  }
  __syncthreads();
  const int lane = tid & 63, wave = tid >> 6;   // 8 waves
  const int l15 = lane & 15, quad = lane >> 4;
  floatx4 acc0 = {0,0,0,0}, acc1 = {0,0,0,0}, acc2 = {0,0,0,0};
  const int g0 = mh * 17 + wave, g1 = g0 + 8, g2 = mh * 17 + 16;
#pragma unroll
  for (int ks = 0; ks < 16; ++ks) {
    short8 bf = *(const short8*)&Xs[l15 * 512 + (((ks * 4 + quad) ^ (l15 & 7)) * 8)];
    short8 af0 = *(const short8*)(TWf + g0 * 8192 + ks * 512 + quad * 128 + l15 * 8);
    short8 af1 = *(const short8*)(TWf + g1 * 8192 + ks * 512 + quad * 128 + l15 * 8);
    acc0 = __builtin_amdgcn_mfma_f32_16x16x32_bf16(af0, bf, acc0, 0, 0, 0);
    acc1 = __builtin_amdgcn_mfma_f32_16x16x32_bf16(af1, bf, acc1, 0, 0, 0);
    if (wave == 0) {
      short8 af2 = *(const short8*)(TWf + g2 * 8192 + ks * 512 + quad * 128 + l15 * 8);
      acc2 = __builtin_amdgcn_mfma_f32_16x16x32_bf16(af2, bf, acc2, 0, 0, 0);
    }
  }
#pragma unroll
  for (int i = 0; i < 3; ++i) {
    if (i == 2 && wave != 0) break;
    const int g = (i == 0) ? g0 : (i == 1) ? g1 : g2;
    floatx4 a = (i == 0) ? acc0 : (i == 1) ? acc1 : acc2;
#pragma unroll
    for (int r = 0; r < 4; ++r) {
      const int grow = g * 16 + quad * 4 + r;
      if (grow < 514) {
        const int k = grow >> 1, ri = grow & 1;
        fftc[((bb * NF_ + k) * 16 + l15) * 2 + ri] =
            a[r] + csd[(bb * NF_ + k) * 2 + ri];
      }
    }
  }
}

// ---------- K4: new_fft + materialize proj as Afrag (bf16, fragment-major).
// grid 2056 x 256 thr (8 blocks/CU -> latency hidden).
__global__ __launch_bounds__(256) void k_new(const float* __restrict__ fftc,
                                             const float* __restrict__ W_proj,
                                             const float* __restrict__ b_proj,
                                             const float* __restrict__ mag_w,
                                             const float* __restrict__ mag_b,
                                             const float* __restrict__ phase_w,
                                             const float* __restrict__ phase_b,
                                             float* __restrict__ nf,
                                             unsigned short* __restrict__ Af) {
  __shared__ float wp[256], bp[64];
  const int tid = threadIdx.x;
  wp[tid] = W_proj[tid];
  if (tid < 64) bp[tid] = b_proj[tid];
  __syncthreads();
  const int idx = blockIdx.x * 256 + tid;
  const int bn = idx >> 4, f = idx & 15;
  const int n = bn % NF_, b = bn / NF_;
  float2 z = *(const float2*)(fftc + idx * 2);
  float d = z.x * z.x + z.y * z.y;
  float ir = d > 0.f ? rsqrtf(d) : 0.f;
  float mag = d * ir;
  float sn = z.y * ir;
  float cs = d > 0.f ? z.x * ir : 1.f;
  float fr = (float)n * 0.1953125f;  // 100/512
  float am = 0.f, ap = 0.f;
  unsigned short* abase = Af + ((size_t)b * NKB + n * 2) * 512 + f * 8;
#pragma unroll
  for (int hg = 0; hg < 8; ++hg) {
    unsigned int w[4];
#pragma unroll
    for (int j = 0; j < 8; ++j) {
      const int h = hg * 8 + j;
      float p = fmaf(mag, wp[h], fmaf(sn, wp[64 + h], fmaf(cs, wp[128 + h],
                fmaf(fr, wp[192 + h], bp[h]))));
      p = fmaxf(p, 0.f);
      am = fmaf(p, mag_w[n * 64 + h], am);
      ap = fmaf(p, phase_w[n * 64 + h], ap);
      unsigned int pb16 = f2bf(p);
      if (j & 1) w[j >> 1] |= pb16 << 16; else w[j >> 1] = pb16;
    }
    *(uint4*)(abase + (hg >> 2) * 512 + (hg & 3) * 128) =
        make_uint4(w[0], w[1], w[2], w[3]);
  }
  float m = fmaxf(am + mag_b[n], 0.f);
  float ph = 6.28318530718f / (1.f + __expf(-(ap + phase_b[n])));
  float sp, cp;
  __sincosf(ph, &sp, &cp);
  *(float2*)(nf + idx * 2) = make_float2(m * cp, m * sp);
}

// ---------- K5: gate GEMM, fragment-streaming, XCD-aware block decode.
// grid 1024 x 256 thr. xcd=bid&7 owns sp in {4*xcd..4*xcd+3}: B working set
// 4 x 328 KB = 1.3 MB -> L2-resident; A streamed once. Block 64m x 320n,
// 4 waves share A-frags, each wave owns 5 B-nblks.
__global__ __launch_bounds__(256) void k_gemm(const unsigned short* __restrict__ Af,
                                              const unsigned short* __restrict__ Bf,
                                              unsigned short* __restrict__ gpart) {
  const int tid = threadIdx.x;
  const int bid = blockIdx.x;
  const int xcd = bid & 7, j = bid >> 3;
  const int sp = xcd * 4 + (j & 3), mg = j >> 2;
  const int lane = tid & 63, wv = tid >> 6;
  const int i0 = (NF_ * sp) >> 5, i1 = (NF_ * (sp + 1)) >> 5;   // pair units (K=64)
  const int nk = (i1 - i0) * 2;            // 16 or 18 (always even)
  const unsigned short* pa = Af + (size_t)(mg * 4) * FRAGS
                             + (size_t)(i0 * 2) * 512 + lane * 8;
  const unsigned short* pb = Bf + (size_t)(wv * 5) * FRAGS
                             + (size_t)(i0 * 2) * 512 + lane * 8;

  floatx4 acc[4][5];
#pragma unroll
  for (int mi = 0; mi < 4; ++mi)
#pragma unroll
    for (int nn = 0; nn < 5; ++nn) acc[mi][nn] = (floatx4){0.f, 0.f, 0.f, 0.f};

  short8 aX[4], aY[4], bX[5], bY[5];
#pragma unroll
  for (int mi = 0; mi < 4; ++mi) {
    aX[mi] = *(const short8*)(pa + (size_t)mi * FRAGS);
    aY[mi] = *(const short8*)(pa + (size_t)mi * FRAGS + 512);
  }
#pragma unroll
  for (int nn = 0; nn < 5; ++nn) {
    bX[nn] = *(const short8*)(pb + (size_t)nn * FRAGS);
    bY[nn] = *(const short8*)(pb + (size_t)nn * FRAGS + 512);
  }
  const int nsteps = (nk - 2) >> 1;
  for (int s = 0; s < nsteps; ++s) {
#pragma unroll
    for (int mi = 0; mi < 4; ++mi)
#pragma unroll
      for (int nn = 0; nn < 5; ++nn)
        acc[mi][nn] = __builtin_amdgcn_mfma_f32_16x16x32_bf16(aX[mi], bX[nn],
                                                              acc[mi][nn], 0, 0, 0);
#pragma unroll
    for (int mi = 0; mi < 4; ++mi) aX[mi] = *(const short8*)(pa + (size_t)mi * FRAGS + 1024);
#pragma unroll
    for (int nn = 0; nn < 5; ++nn) bX[nn] = *(const short8*)(pb + (size_t)nn * FRAGS + 1024);
#pragma unroll
    for (int mi = 0; mi < 4; ++mi)
#pragma unroll
      for (int nn = 0; nn < 5; ++nn)
        acc[mi][nn] = __builtin_amdgcn_mfma_f32_16x16x32_bf16(aY[mi], bY[nn],
                                                              acc[mi][nn], 0, 0, 0);
#pragma unroll
    for (int mi = 0; mi < 4; ++mi) aY[mi] = *(const short8*)(pa + (size_t)mi * FRAGS + 1536);
#pragma unroll
    for (int nn = 0; nn < 5; ++nn) bY[nn] = *(const short8*)(pb + (size_t)nn * FRAGS + 1536);
    pa += 1024; pb += 1024;
  }
#pragma unroll
  for (int mi = 0; mi < 4; ++mi)
#pragma unroll
    for (int nn = 0; nn < 5; ++nn)
      acc[mi][nn] = __builtin_amdgcn_mfma_f32_16x16x32_bf16(aX[mi], bX[nn],
                                                            acc[mi][nn], 0, 0, 0);
#pragma unroll
  for (int mi = 0; mi < 4; ++mi)
#pragma unroll
    for (int nn = 0; nn < 5; ++nn)
      acc[mi][nn] = __builtin_amdgcn_mfma_f32_16x16x32_bf16(aY[mi], bY[nn],
                                                            acc[mi][nn], 0, 0, 0);

  // fragment-major partial store: coalesced 8B/lane.
#pragma unroll
  for (int mi = 0; mi < 4; ++mi)
#pragma unroll
    for (int nn = 0; nn < 5; ++nn) {
      unsigned int lo = f2bf(acc[mi][nn][0]) | (f2bf(acc[mi][nn][1]) << 16);
      unsigned int hi = f2bf(acc[mi][nn][2]) | (f2bf(acc[mi][nn][3]) << 16);
      *(uint2*)(gpart + (((size_t)sp * 128 + mg * 4 + mi) * 20 + wv * 5 + nn) * 256
                + lane * 4) = make_uint2(lo, hi);
    }
}

// ---------- K6: irfft GEMM + fused split-K w-reduction (depth SPK=32).
// grid (2,128) x 512 thr. out = LN(ITWf x WF^T + x).
__global__ __launch_bounds__(512) void k_recong(const float* __restrict__ fftc,
                                                const float* __restrict__ nfb,
                                                const unsigned short* __restrict__ gpart,
                                                const float* __restrict__ b_gate,
                                                const unsigned short* __restrict__ ITWf,
                                                const float* __restrict__ x,
                                                const float* __restrict__ ln_g,
                                                const float* __restrict__ ln_b,
                                                float* __restrict__ out) {
  __shared__ __align__(16) unsigned short WFs[16 * 576];
  __shared__ float wls[16 * 257];
  const int tid = threadIdx.x, th = blockIdx.x, bb = blockIdx.y;
  // fused w-reduction: sum SPK partials from gpart fragment layout.
  const unsigned short* gpb = gpart + (size_t)bb * 5120;   // mfrag = bb
  for (int t = tid; t < 1088; t += 512) {
    const int n = ((t >> 6) << 4) + (t & 15);
    if (n < NF_) {
      const int quad = (t >> 4) & 3;
      const float bg = b_gate[n];
      float g0 = bg, g1 = bg, g2 = bg, g3 = bg;
#pragma unroll
      for (int s2 = 0; s2 < SPK; ++s2) {
        uint2 v = *(const uint2*)(gpb + (size_t)s2 * 655360 + (size_t)t * 4);
        g0 += bf2f(v.x & 0xFFFFu); g1 += bf2f(v.x >> 16);
        g2 += bf2f(v.y & 0xFFFFu); g3 += bf2f(v.y >> 16);
      }
      float gv[4] = {g0, g1, g2, g3};
#pragma unroll
      for (int r = 0; r < 4; ++r) {
        float g = gv[r];
        float sg = 1.f / (1.f + __expf(-g));
        float gs = g * sg;
        wls[(quad * 4 + r) * 257 + n] = 1.f / (1.f + __expf(-gs));
      }
    }
  }
  __syncthreads();
#pragma unroll
  for (int it = 0; it < 17; ++it) {
    int e = it * 512 + tid;        // < 8704 = 16*544
    int f = e & 15, row = e >> 4;
    float val = 0.f;
    if (row < 514) {
      int k = row >> 1, ri = row & 1;
      int base = ((bb * NF_ + k) * 16 + f) * 2 + ri;
      float fz = fftc[base], nz = nfb[base];
      float wv = wls[f * 257 + k];
      val = fz + wv * (nz - fz);
    }
    WFs[f * 576 + (((row >> 3) ^ (f & 7)) * 8) + (row & 7)] = (unsigned short)f2bf(val);
  }
  __syncthreads();
  const int lane = tid & 63, wave = tid >> 6;   // 8 waves x 2 tiles
  const int l15 = lane & 15, quad = lane >> 4;
  const float gg = ln_g[l15], gb = ln_b[l15];
  floatx4 acc[2];
  acc[0] = (floatx4){0.f, 0.f, 0.f, 0.f};
  acc[1] = (floatx4){0.f, 0.f, 0.f, 0.f};
  const int tg0 = th * 16 + wave, tg1 = tg0 + 8;
#pragma unroll
  for (int ks = 0; ks < 17; ++ks) {
    short8 bf = *(const short8*)&WFs[l15 * 576 + (((ks * 4 + quad) ^ (l15 & 7)) * 8)];
    short8 af0 = *(const short8*)(ITWf + tg0 * 8704 + ks * 512 + quad * 128 + l15 * 8);
    short8 af1 = *(const short8*)(ITWf + tg1 * 8704 + ks * 512 + quad * 128 + l15 * 8);
    acc[0] = __builtin_amdgcn_mfma_f32_16x16x32_bf16(af0, bf, acc[0], 0, 0, 0);
    acc[1] = __builtin_amdgcn_mfma_f32_16x16x32_bf16(af1, bf, acc[1], 0, 0, 0);
  }
#pragma unroll
  for (int i = 0; i < 2; ++i) {
    const int tg = (i == 0) ? tg0 : tg1;
#pragma unroll
    for (int r = 0; r < 4; ++r) {
      const int t = tg * 16 + quad * 4 + r;
      float y = acc[i][r] + x[(bb * 512 + t) * 16 + l15];
      float s1 = y, s2 = y * y;
#pragma unroll
      for (int m = 1; m < 16; m <<= 1) {
        s1 += __shfl_xor(s1, m);
        s2 += __shfl_xor(s2, m);
      }
      float mu = s1 * 0.0625f;
      float var = s2 * 0.0625f - mu * mu;
      float rs = rsqrtf(var + 1e-5f);
      out[(bb * 512 + t) * 16 + l15] = (y - mu) * rs * gg + gb;
    }
  }
}

extern "C" void kernel_launch(void* const* d_in, const int* in_sizes, int n_in,
                              void* d_out, int out_size, void* d_ws, size_t ws_size,
                              hipStream_t stream) {
  const float* x = (const float*)d_in[0];
  const float* W_proj = (const float*)d_in[1];
  const float* b_proj = (const float*)d_in[2];
  const float* W_gate = (const float*)d_in[3];
  const float* b_gate = (const float*)d_in[4];
  const float* mag_w = (const float*)d_in[5];
  const float* mag_b = (const float*)d_in[6];
  const float* phase_w = (const float*)d_in[7];
  const float* phase_b = (const float*)d_in[8];
  const float* ln_g = (const float*)d_in[9];
  const float* ln_b = (const float*)d_in[10];
  float* out = (float*)d_out;
  float* ws = (float*)d_ws;

  // workspace (float slots), ~132 MB total (ws = 256 MB)
  float* fftc = ws;                                          // 1,052,672 f
  float* nfb = ws + 1052672;                                 // 1,052,672 f
  float* csd = ws + 2631680;                                 //    65,792 f
  unsigned short* Afrag = (unsigned short*)(ws + 2697472);   // 33,685,504 sh (67.4 MB)
  unsigned short* Bfrag = (unsigned short*)(ws + 19540224);  //  5,263,360 sh (10.5 MB)
  unsigned short* gpart = (unsigned short*)(ws + 22171904);  // 20,971,520 sh (42.0 MB)
  unsigned short* TWf = (unsigned short*)(ws + 32657664);    //    278,528 sh
  unsigned short* ITWf = (unsigned short*)(ws + 32796928);   //    278,528 sh

  hipLaunchKernelGGL(k_prep, dim3(2970), dim3(256), 0, stream,
                     x, W_gate, csd, Bfrag, TWf, ITWf);
  hipLaunchKernelGGL(k_fftg, dim3(2, 128), dim3(512), 0, stream, x, TWf, csd, fftc);
  hipLaunchKernelGGL(k_new, dim3(2056), dim3(256), 0, stream, fftc, W_proj, b_proj,
                     mag_w, mag_b, phase_w, phase_b, nfb, Afrag);
  hipLaunchKernelGGL(k_gemm, dim3(1024), dim3(256), 0, stream, Afrag, Bfrag, gpart);
  hipLaunchKernelGGL(k_recong, dim3(2, 128), dim3(512), 0, stream, fftc, nfb, gpart,
                     b_gate, ITWf, x, ln_g, ln_b, out);
}

// Round 8
// 183.538 us; speedup vs baseline: 1.0663x; 1.0663x over previous
//
#include <hip/hip_runtime.h>

// AdaptiveSpectrumLayer: B=128, H=T=512, F=16, NF=257
// v14 (resubmit; round-7 run died to container failure, not kernel):
//  - unfused spectral stage: k_fftg (GEMM, 256 blocks) + k_new (proj/Afrag,
//    2056 blocks, 8/CU) -- v12 measured fused k_spec at 42 µs, 1.9 TB/s,
//    1 block/CU; split runs the 74 MB Afrag write at full occupancy.
//  - k_gemm: v10's LDS-staged double-buffered gemm (SPK16, grid (16,32),
//    launch_bounds(256,2)) -- inferred ~26-30 µs vs 43.6 measured streaming.
//  - no XCD decode (v13's hurt ~+13 µs). SPK=16, gpart 21 MB.

#define NF_ 257
#define NKB 514          // K blocks of 32: NF_*64/32
#define FRAGS 263168     // NKB*512 shorts: stride between m/n blocks in frag space
#define SPK 16
#define SORTHO 0.04419417382f   // 1/sqrt(512)

typedef __attribute__((ext_vector_type(8))) short short8;
typedef __attribute__((ext_vector_type(4))) float floatx4;

__device__ __forceinline__ unsigned int f2bf(float x) {
  union { float f; unsigned int u; } v; v.f = x;
  return (v.u + 0x7FFFu + ((v.u >> 16) & 1u)) >> 16;
}
__device__ __forceinline__ float bf2f(unsigned int u16) {
  union { unsigned int u; float f; } v; v.u = u16 << 16;
  return v.f;
}

// ---------- K_prep: fused {csd | wgt | tw | itw} by blockIdx range.
// blocks [0,128): csd; [128,2698): wgt; [2698,2834): tw; [2834,2970): itw.
__global__ __launch_bounds__(256) void k_prep(const float* __restrict__ x,
                                              const float* __restrict__ Wg,
                                              float* __restrict__ csd,
                                              unsigned short* __restrict__ Bf,
                                              unsigned short* __restrict__ TWf,
                                              unsigned short* __restrict__ ITWf) {
  __shared__ float sl[768];
  __shared__ float ac[257];
  __shared__ float red[4];
  const int tid = threadIdx.x;
  const int blk = blockIdx.x;

  if (blk < 128) {
    // ---- csd[b][k] = (1/(256*sqrt(512))) * DFT_t( autocorr(s)[t-255] )
    const int bb = blk;
    for (int t = tid; t < 768; t += 256) {
      float v = 0.f;
      if (t < 512) {
        const float4* xp = (const float4*)(x + (bb * 512 + t) * 16);
        float4 a = xp[0], b = xp[1], c = xp[2], d = xp[3];
        v = a.x + a.y + a.z + a.w + b.x + b.y + b.z + b.w +
            c.x + c.y + c.z + c.w + d.x + d.y + d.z + d.w;
      }
      sl[t] = v;
    }
    __syncthreads();
    {
      float a0 = 0.f, a1 = 0.f, a2 = 0.f, a3 = 0.f;
      for (int tau = 0; tau < 512; tau += 4) {
        float4 u = *(const float4*)&sl[tau];
        a0 = fmaf(u.x, sl[tau + tid], a0);
        a1 = fmaf(u.y, sl[tau + tid + 1], a1);
        a2 = fmaf(u.z, sl[tau + tid + 2], a2);
        a3 = fmaf(u.w, sl[tau + tid + 3], a3);
      }
      ac[tid] = (a0 + a1) + (a2 + a3);
    }
    {
      float p = sl[tid] * sl[tid + 256];
#pragma unroll
      for (int off = 32; off; off >>= 1) p += __shfl_down(p, off);
      if ((tid & 63) == 0) red[tid >> 6] = p;
    }
    __syncthreads();
    if (tid == 0) ac[256] = red[0] + red[1] + red[2] + red[3];
    __syncthreads();
    const float S1 = SORTHO / 256.f;
    const int k = tid;            // 0..255; k=256 via exact alternating chain
    float sth, cth;
    __sincosf((float)k * 0.01227184630f, &sth, &cth);
    float c = 1.f, s = 0.f, re = 0.f, im = 0.f;
    float re256 = 0.f, sg = 1.f;
    for (int t = 0; t < 512; ++t) {
      int d = t - 255;
      float ov = ac[d < 0 ? -d : d];
      re = fmaf(ov, c, re);
      im = fmaf(-ov, s, im);
      re256 = fmaf(ov, sg, re256);
      sg = -sg;
      float nc = fmaf(c, cth, -s * sth);
      s = fmaf(s, cth, c * sth);
      c = nc;
    }
    *(float2*)(csd + (bb * NF_ + k) * 2) = make_float2(re * S1, im * S1);
    if (tid == 0)
      *(float2*)(csd + (bb * NF_ + 256) * 2) = make_float2(re256 * S1, 0.f);
    return;
  }

  if (blk < 2698) {
    // ---- W_gate (16448 x 257 f32) -> Bfrag bf16 fragment-major.
    const int slot = (blk - 128) * 256 + tid;          // < 657920
    const int nblk = slot / 32896;                     // 514*64
    const int rem = slot - nblk * 32896;
    const int kb = rem >> 6, lane = rem & 63;
    const int n = nblk * 16 + (lane & 15);
    const int k0 = kb * 32 + (lane >> 4) * 8;
    unsigned int w[4];
#pragma unroll
    for (int jp = 0; jp < 4; ++jp) {
      float v0 = (n < NF_) ? Wg[(k0 + jp * 2) * NF_ + n] : 0.f;
      float v1 = (n < NF_) ? Wg[(k0 + jp * 2 + 1) * NF_ + n] : 0.f;
      w[jp] = f2bf(v0) | (f2bf(v1) << 16);
    }
    *(uint4*)(Bf + (size_t)slot * 8) = make_uint4(w[0], w[1], w[2], w[3]);
    return;
  }

  if (blk < 2834) {
    // ---- rfft twiddle table, fragment-major, S folded.
    const int slot = (blk - 2698) * 256 + tid;   // < 34816
    const int tile = slot >> 10, rem = slot & 1023;
    const int ks = rem >> 6, quad = (rem >> 4) & 3, l15 = rem & 15;
    const int grow = tile * 16 + l15;
    unsigned int pk[4];
#pragma unroll
    for (int jp = 0; jp < 4; ++jp) {
      float v0 = 0.f, v1 = 0.f;
      if (grow < 514) {
        const int k = grow >> 1;
        const int t0 = ks * 32 + quad * 8 + jp * 2;
        float s0, c0, s1, c1;
        __sincosf((float)((k * t0) & 511) * 0.01227184630f, &s0, &c0);
        __sincosf((float)((k * (t0 + 1)) & 511) * 0.01227184630f, &s1, &c1);
        v0 = (grow & 1) ? -s0 * SORTHO : c0 * SORTHO;
        v1 = (grow & 1) ? -s1 * SORTHO : c1 * SORTHO;
      }
      pk[jp] = f2bf(v0) | (f2bf(v1) << 16);
    }
    *(uint4*)(TWf + slot * 8) = make_uint4(pk[0], pk[1], pk[2], pk[3]);
    return;
  }

  {
    // ---- irfft twiddle table, fragment-major, S + Hermitian folded.
    const int slot = (blk - 2834) * 256 + tid;   // < 34816
    const int tile = slot / 1088, rem = slot % 1088;
    const int ks = rem >> 6, sub = rem & 63;
    const int quad = sub >> 4, l15 = sub & 15;
    const int t = tile * 16 + l15;
    unsigned int pk[4];
#pragma unroll
    for (int jp = 0; jp < 4; ++jp) {
      float v0 = 0.f, v1 = 0.f;
#pragma unroll
      for (int h = 0; h < 2; ++h) {
        const int kidx = ks * 32 + quad * 8 + jp * 2 + h;
        float v = 0.f;
        if (kidx < 514) {
          const int k = kidx >> 1;
          const float hw = (k == 0 || k == 256) ? SORTHO : 2.f * SORTHO;
          float s, c;
          __sincosf((float)((k * t) & 511) * 0.01227184630f, &s, &c);
          v = (kidx & 1) ? -s * hw : c * hw;
        }
        if (h == 0) v0 = v; else v1 = v;
      }
      pk[jp] = f2bf(v0) | (f2bf(v1) << 16);
    }
    *(uint4*)(ITWf + slot * 8) = make_uint4(pk[0], pk[1], pk[2], pk[3]);
  }
}

// ---------- K3: rfft GEMM: fftc = TWf x X^T + csd. grid (2,128) x 512 thr.
__global__ __launch_bounds__(512) void k_fftg(const float* __restrict__ x,
                                              const unsigned short* __restrict__ TWf,
                                              const float* __restrict__ csd,
                                              float* __restrict__ fftc) {
  __shared__ __align__(16) unsigned short Xs[16 * 512];
  const int tid = threadIdx.x, mh = blockIdx.x, bb = blockIdx.y;
#pragma unroll
  for (int it = 0; it < 16; ++it) {
    int e = it * 512 + tid;
    int f = e & 15, t = e >> 4;
    float val = x[(bb * 512 + t) * 16 + f];
    Xs[f * 512 + (((t >> 3) ^ (f & 7)) * 8) + (t & 7)] = (unsigned short)f2bf(val);
  }
  __syncthreads();
  const int lane = tid & 63, wave = tid >> 6;   // 8 waves
  const int l15 = lane & 15, quad = lane >> 4;
  floatx4 acc0 = {0,0,0,0}, acc1 = {0,0,0,0}, acc2 = {0,0,0,0};
  const int g0 = mh * 17 + wave, g1 = g0 + 8, g2 = mh * 17 + 16;
#pragma unroll
  for (int ks = 0; ks < 16; ++ks) {
    short8 bf = *(const short8*)&Xs[l15 * 512 + (((ks * 4 + quad) ^ (l15 & 7)) * 8)];
    short8 af0 = *(const short8*)(TWf + g0 * 8192 + ks * 512 + quad * 128 + l15 * 8);
    short8 af1 = *(const short8*)(TWf + g1 * 8192 + ks * 512 + quad * 128 + l15 * 8);
    acc0 = __builtin_amdgcn_mfma_f32_16x16x32_bf16(af0, bf, acc0, 0, 0, 0);
    acc1 = __builtin_amdgcn_mfma_f32_16x16x32_bf16(af1, bf, acc1, 0, 0, 0);
    if (wave == 0) {
      short8 af2 = *(const short8*)(TWf + g2 * 8192 + ks * 512 + quad * 128 + l15 * 8);
      acc2 = __builtin_amdgcn_mfma_f32_16x16x32_bf16(af2, bf, acc2, 0, 0, 0);
    }
  }
#pragma unroll
  for (int i = 0; i < 3; ++i) {
    if (i == 2 && wave != 0) break;
    const int g = (i == 0) ? g0 : (i == 1) ? g1 : g2;
    floatx4 a = (i == 0) ? acc0 : (i == 1) ? acc1 : acc2;
#pragma unroll
    for (int r = 0; r < 4; ++r) {
      const int grow = g * 16 + quad * 4 + r;
      if (grow < 514) {
        const int k = grow >> 1, ri = grow & 1;
        fftc[((bb * NF_ + k) * 16 + l15) * 2 + ri] =
            a[r] + csd[(bb * NF_ + k) * 2 + ri];
      }
    }
  }
}

// ---------- K4: new_fft + materialize proj as Afrag (bf16, fragment-major).
// grid 2056 x 256 thr (8 blocks/CU -> write-BW bound at full occupancy).
__global__ __launch_bounds__(256) void k_new(const float* __restrict__ fftc,
                                             const float* __restrict__ W_proj,
                                             const float* __restrict__ b_proj,
                                             const float* __restrict__ mag_w,
                                             const float* __restrict__ mag_b,
                                             const float* __restrict__ phase_w,
                                             const float* __restrict__ phase_b,
                                             float* __restrict__ nf,
                                             unsigned short* __restrict__ Af) {
  __shared__ float wp[256], bp[64];
  const int tid = threadIdx.x;
  wp[tid] = W_proj[tid];
  if (tid < 64) bp[tid] = b_proj[tid];
  __syncthreads();
  const int idx = blockIdx.x * 256 + tid;
  const int bn = idx >> 4, f = idx & 15;
  const int n = bn % NF_, b = bn / NF_;
  float2 z = *(const float2*)(fftc + idx * 2);
  float d = z.x * z.x + z.y * z.y;
  float ir = d > 0.f ? rsqrtf(d) : 0.f;
  float mag = d * ir;
  float sn = z.y * ir;
  float cs = d > 0.f ? z.x * ir : 1.f;
  float fr = (float)n * 0.1953125f;  // 100/512
  float am = 0.f, ap = 0.f;
  unsigned short* abase = Af + ((size_t)b * NKB + n * 2) * 512 + f * 8;
#pragma unroll
  for (int hg = 0; hg < 8; ++hg) {
    unsigned int w[4];
#pragma unroll
    for (int j = 0; j < 8; ++j) {
      const int h = hg * 8 + j;
      float p = fmaf(mag, wp[h], fmaf(sn, wp[64 + h], fmaf(cs, wp[128 + h],
                fmaf(fr, wp[192 + h], bp[h]))));
      p = fmaxf(p, 0.f);
      am = fmaf(p, mag_w[n * 64 + h], am);
      ap = fmaf(p, phase_w[n * 64 + h], ap);
      unsigned int pb16 = f2bf(p);
      if (j & 1) w[j >> 1] |= pb16 << 16; else w[j >> 1] = pb16;
    }
    *(uint4*)(abase + (hg >> 2) * 512 + (hg & 3) * 128) =
        make_uint4(w[0], w[1], w[2], w[3]);
  }
  float m = fmaxf(am + mag_b[n], 0.f);
  float ph = 6.28318530718f / (1.f + __expf(-(ap + phase_b[n])));
  float sp, cp;
  __sincosf(ph, &sp, &cp);
  *(float2*)(nf + idx * 2) = make_float2(m * cp, m * sp);
}

// ---------- K5: gate GEMM with LDS-staged A (v10's proven variant).
// grid (16 sp, 32 mgg) x 256. Per step (2 kfrags): stage A 8KB to LDS
// (reg-staged, double-buffered), raw s_barrier (lgkmcnt only), B direct->reg.
__global__ __launch_bounds__(256, 2) void k_gemm(const unsigned short* __restrict__ Af,
                                                 const unsigned short* __restrict__ Bf,
                                                 unsigned short* __restrict__ gpart) {
  __shared__ __align__(16) unsigned short As[2][4096];  // [buf][(kf*4+mi)*512 + lane*8]
  const int tid = threadIdx.x;
  const int sp = blockIdx.x, mgg = blockIdx.y;
  const int lane = tid & 63, wv = tid >> 6;
  const int p0 = (NF_ * sp) >> 4, p1 = (NF_ * (sp + 1)) >> 4;
  const int nsteps = p1 - p0;                 // 16 or 17 (kfrag pairs)
  const int c0 = wv * 2, c1 = wv * 2 + 1;     // chunk = kf*4 + mi
  const unsigned short* aSrc0 = Af + (size_t)(mgg * 4 + (c0 & 3)) * FRAGS
                                + (size_t)(p0 * 2 + (c0 >> 2)) * 512 + lane * 8;
  const unsigned short* aSrc1 = Af + (size_t)(mgg * 4 + (c1 & 3)) * FRAGS
                                + (size_t)(p0 * 2 + (c1 >> 2)) * 512 + lane * 8;
  const unsigned short* pb = Bf + (size_t)(wv * 5) * FRAGS
                             + (size_t)(p0 * 2) * 512 + lane * 8;

  floatx4 acc[4][5];
#pragma unroll
  for (int mi = 0; mi < 4; ++mi)
#pragma unroll
    for (int nn = 0; nn < 5; ++nn) acc[mi][nn] = (floatx4){0.f, 0.f, 0.f, 0.f};

  uint4 ra0 = *(const uint4*)aSrc0;
  uint4 ra1 = *(const uint4*)aSrc1;
  short8 bX[5], bY[5];
#pragma unroll
  for (int nn = 0; nn < 5; ++nn) {
    bX[nn] = *(const short8*)(pb + (size_t)nn * FRAGS);
    bY[nn] = *(const short8*)(pb + (size_t)nn * FRAGS + 512);
  }

  for (int s = 0; s < nsteps; ++s) {
    unsigned short* dst = &As[s & 1][0];
    *(uint4*)(dst + c0 * 512 + lane * 8) = ra0;
    *(uint4*)(dst + c1 * 512 + lane * 8) = ra1;
    if (s + 1 < nsteps) {
      aSrc0 += 1024; aSrc1 += 1024;
      ra0 = *(const uint4*)aSrc0;
      ra1 = *(const uint4*)aSrc1;
    }
    __builtin_amdgcn_sched_barrier(0);
    asm volatile("s_waitcnt lgkmcnt(0)" ::: "memory");
    __builtin_amdgcn_s_barrier();
    __builtin_amdgcn_sched_barrier(0);
    const unsigned short* rb = &As[s & 1][0];
    {
      short8 a0 = *(const short8*)(rb + 0 * 512 + lane * 8);
      short8 a1 = *(const short8*)(rb + 1 * 512 + lane * 8);
      short8 a2 = *(const short8*)(rb + 2 * 512 + lane * 8);
      short8 a3 = *(const short8*)(rb + 3 * 512 + lane * 8);
#pragma unroll
      for (int nn = 0; nn < 5; ++nn) {
        acc[0][nn] = __builtin_amdgcn_mfma_f32_16x16x32_bf16(a0, bX[nn], acc[0][nn], 0, 0, 0);
        acc[1][nn] = __builtin_amdgcn_mfma_f32_16x16x32_bf16(a1, bX[nn], acc[1][nn], 0, 0, 0);
        acc[2][nn] = __builtin_amdgcn_mfma_f32_16x16x32_bf16(a2, bX[nn], acc[2][nn], 0, 0, 0);
        acc[3][nn] = __builtin_amdgcn_mfma_f32_16x16x32_bf16(a3, bX[nn], acc[3][nn], 0, 0, 0);
      }
      if (s + 1 < nsteps) {
#pragma unroll
        for (int nn = 0; nn < 5; ++nn)
          bX[nn] = *(const short8*)(pb + (size_t)nn * FRAGS + 1024);
      }
    }
    {
      short8 a0 = *(const short8*)(rb + 4 * 512 + lane * 8);
      short8 a1 = *(const short8*)(rb + 5 * 512 + lane * 8);
      short8 a2 = *(const short8*)(rb + 6 * 512 + lane * 8);
      short8 a3 = *(const short8*)(rb + 7 * 512 + lane * 8);
#pragma unroll
      for (int nn = 0; nn < 5; ++nn) {
        acc[0][nn] = __builtin_amdgcn_mfma_f32_16x16x32_bf16(a0, bY[nn], acc[0][nn], 0, 0, 0);
        acc[1][nn] = __builtin_amdgcn_mfma_f32_16x16x32_bf16(a1, bY[nn], acc[1][nn], 0, 0, 0);
        acc[2][nn] = __builtin_amdgcn_mfma_f32_16x16x32_bf16(a2, bY[nn], acc[2][nn], 0, 0, 0);
        acc[3][nn] = __builtin_amdgcn_mfma_f32_16x16x32_bf16(a3, bY[nn], acc[3][nn], 0, 0, 0);
      }
      if (s + 1 < nsteps) {
#pragma unroll
        for (int nn = 0; nn < 5; ++nn)
          bY[nn] = *(const short8*)(pb + (size_t)nn * FRAGS + 1536);
        pb += 1024;
      }
    }
  }

  // fragment-major partial store: coalesced 8B/lane.
#pragma unroll
  for (int mi = 0; mi < 4; ++mi)
#pragma unroll
    for (int nn = 0; nn < 5; ++nn) {
      unsigned int lo = f2bf(acc[mi][nn][0]) | (f2bf(acc[mi][nn][1]) << 16);
      unsigned int hi = f2bf(acc[mi][nn][2]) | (f2bf(acc[mi][nn][3]) << 16);
      *(uint2*)(gpart + ((((size_t)sp * 128 + mgg * 4 + mi) * 20) + wv * 5 + nn) * 256
                + lane * 4) = make_uint2(lo, hi);
    }
}

// ---------- K6: irfft GEMM + fused split-K w-reduction (depth SPK=16).
// grid (2,128) x 512 thr. out = LN(ITWf x WF^T + x).
__global__ __launch_bounds__(512) void k_recong(const float* __restrict__ fftc,
                                                const float* __restrict__ nfb,
                                                const unsigned short* __restrict__ gpart,
                                                const float* __restrict__ b_gate,
                                                const unsigned short* __restrict__ ITWf,
                                                const float* __restrict__ x,
                                                const float* __restrict__ ln_g,
                                                const float* __restrict__ ln_b,
                                                float* __restrict__ out) {
  __shared__ __align__(16) unsigned short WFs[16 * 576];
  __shared__ float wls[16 * 257];
  const int tid = threadIdx.x, th = blockIdx.x, bb = blockIdx.y;
  // fused w-reduction: sum SPK partials from gpart fragment layout.
  const unsigned short* gpb = gpart + (size_t)bb * 5120;   // mfrag = bb
  for (int t = tid; t < 1088; t += 512) {
    const int n = ((t >> 6) << 4) + (t & 15);
    if (n < NF_) {
      const int quad = (t >> 4) & 3;
      const float bg = b_gate[n];
      float g0 = bg, g1 = bg, g2 = bg, g3 = bg;
#pragma unroll
      for (int s2 = 0; s2 < SPK; ++s2) {
        uint2 v = *(const uint2*)(gpb + (size_t)s2 * 655360 + (size_t)t * 4);
        g0 += bf2f(v.x & 0xFFFFu); g1 += bf2f(v.x >> 16);
        g2 += bf2f(v.y & 0xFFFFu); g3 += bf2f(v.y >> 16);
      }
      float gv[4] = {g0, g1, g2, g3};
#pragma unroll
      for (int r = 0; r < 4; ++r) {
        float g = gv[r];
        float sg = 1.f / (1.f + __expf(-g));
        float gs = g * sg;
        wls[(quad * 4 + r) * 257 + n] = 1.f / (1.f + __expf(-gs));
      }
    }
  }
  __syncthreads();
#pragma unroll
  for (int it = 0; it < 17; ++it) {
    int e = it * 512 + tid;        // < 8704 = 16*544
    int f = e & 15, row = e >> 4;
    float val = 0.f;
    if (row < 514) {
      int k = row >> 1, ri = row & 1;
      int base = ((bb * NF_ + k) * 16 + f) * 2 + ri;
      float fz = fftc[base], nz = nfb[base];
      float wv = wls[f * 257 + k];
      val = fz + wv * (nz - fz);
    }
    WFs[f * 576 + (((row >> 3) ^ (f & 7)) * 8) + (row & 7)] = (unsigned short)f2bf(val);
  }
  __syncthreads();
  const int lane = tid & 63, wave = tid >> 6;   // 8 waves x 2 tiles
  const int l15 = lane & 15, quad = lane >> 4;
  const float gg = ln_g[l15], gb = ln_b[l15];
  floatx4 acc[2];
  acc[0] = (floatx4){0.f, 0.f, 0.f, 0.f};
  acc[1] = (floatx4){0.f, 0.f, 0.f, 0.f};
  const int tg0 = th * 16 + wave, tg1 = tg0 + 8;
#pragma unroll
  for (int ks = 0; ks < 17; ++ks) {
    short8 bf = *(const short8*)&WFs[l15 * 576 + (((ks * 4 + quad) ^ (l15 & 7)) * 8)];
    short8 af0 = *(const short8*)(ITWf + tg0 * 8704 + ks * 512 + quad * 128 + l15 * 8);
    short8 af1 = *(const short8*)(ITWf + tg1 * 8704 + ks * 512 + quad * 128 + l15 * 8);
    acc[0] = __builtin_amdgcn_mfma_f32_16x16x32_bf16(af0, bf, acc[0], 0, 0, 0);
    acc[1] = __builtin_amdgcn_mfma_f32_16x16x32_bf16(af1, bf, acc[1], 0, 0, 0);
  }
#pragma unroll
  for (int i = 0; i < 2; ++i) {
    const int tg = (i == 0) ? tg0 : tg1;
#pragma unroll
    for (int r = 0; r < 4; ++r) {
      const int t = tg * 16 + quad * 4 + r;
      float y = acc[i][r] + x[(bb * 512 + t) * 16 + l15];
      float s1 = y, s2 = y * y;
#pragma unroll
      for (int m = 1; m < 16; m <<= 1) {
        s1 += __shfl_xor(s1, m);
        s2 += __shfl_xor(s2, m);
      }
      float mu = s1 * 0.0625f;
      float var = s2 * 0.0625f - mu * mu;
      float rs = rsqrtf(var + 1e-5f);
      out[(bb * 512 + t) * 16 + l15] = (y - mu) * rs * gg + gb;
    }
  }
}

extern "C" void kernel_launch(void* const* d_in, const int* in_sizes, int n_in,
                              void* d_out, int out_size, void* d_ws, size_t ws_size,
                              hipStream_t stream) {
  const float* x = (const float*)d_in[0];
  const float* W_proj = (const float*)d_in[1];
  const float* b_proj = (const float*)d_in[2];
  const float* W_gate = (const float*)d_in[3];
  const float* b_gate = (const float*)d_in[4];
  const float* mag_w = (const float*)d_in[5];
  const float* mag_b = (const float*)d_in[6];
  const float* phase_w = (const float*)d_in[7];
  const float* phase_b = (const float*)d_in[8];
  const float* ln_g = (const float*)d_in[9];
  const float* ln_b = (const float*)d_in[10];
  float* out = (float*)d_out;
  float* ws = (float*)d_ws;

  // workspace (float slots)
  float* fftc = ws;                                          // 1,052,672 f
  float* nfb = ws + 1052672;                                 // 1,052,672 f
  float* csd = ws + 2631680;                                 //    65,792 f
  unsigned short* Afrag = (unsigned short*)(ws + 2697472);   // 33,685,504 sh (67.4 MB)
  unsigned short* Bfrag = (unsigned short*)(ws + 19540224);  //  5,263,360 sh (10.5 MB)
  unsigned short* gpart = (unsigned short*)(ws + 22171904);  // 10,485,760 sh (21.0 MB)
  unsigned short* TWf = (unsigned short*)(ws + 27414784);    //    278,528 sh
  unsigned short* ITWf = (unsigned short*)(ws + 27554048);   //    278,528 sh

  hipLaunchKernelGGL(k_prep, dim3(2970), dim3(256), 0, stream,
                     x, W_gate, csd, Bfrag, TWf, ITWf);
  hipLaunchKernelGGL(k_fftg, dim3(2, 128), dim3(512), 0, stream, x, TWf, csd, fftc);
  hipLaunchKernelGGL(k_new, dim3(2056), dim3(256), 0, stream, fftc, W_proj, b_proj,
                     mag_w, mag_b, phase_w, phase_b, nfb, Afrag);
  hipLaunchKernelGGL(k_gemm, dim3(16, 32), dim3(256), 0, stream, Afrag, Bfrag, gpart);
  hipLaunchKernelGGL(k_recong, dim3(2, 128), dim3(512), 0, stream, fftc, nfb, gpart,
                     b_gate, ITWf, x, ln_g, ln_b, out);
}

// Round 9
// 181.353 us; speedup vs baseline: 1.0792x; 1.0120x over previous
//
#include <hip/hip_runtime.h>

// AdaptiveSpectrumLayer: B=128, H=T=512, F=16, NF=257
// v15: Afrag eliminated. k_gemm computes proj in-kernel during the LDS staging
//      phase (each (b,n,f,h) belongs to exactly one (sp,mgg) block -> zero
//      recompute); barrier/double-buffer structure identical to v10/v14's
//      proven loop. k_new shrinks to nfb-only (no 67 MB Afrag write).
//      Saves the 134 MB Afrag HBM round-trip (~21 µs floor).

#define NF_ 257
#define FRAGS 263168     // NKB*512 shorts: stride between n-blocks in Bfrag
#define SPK 16
#define SORTHO 0.04419417382f   // 1/sqrt(512)

typedef __attribute__((ext_vector_type(8))) short short8;
typedef __attribute__((ext_vector_type(4))) float floatx4;

__device__ __forceinline__ unsigned int f2bf(float x) {
  union { float f; unsigned int u; } v; v.f = x;
  return (v.u + 0x7FFFu + ((v.u >> 16) & 1u)) >> 16;
}
__device__ __forceinline__ float bf2f(unsigned int u16) {
  union { unsigned int u; float f; } v; v.u = u16 << 16;
  return v.f;
}

// ---------- K_prep: fused {csd | wgt | tw | itw} by blockIdx range.
// blocks [0,128): csd; [128,2698): wgt; [2698,2834): tw; [2834,2970): itw.
__global__ __launch_bounds__(256) void k_prep(const float* __restrict__ x,
                                              const float* __restrict__ Wg,
                                              float* __restrict__ csd,
                                              unsigned short* __restrict__ Bf,
                                              unsigned short* __restrict__ TWf,
                                              unsigned short* __restrict__ ITWf) {
  __shared__ float sl[768];
  __shared__ float ac[257];
  __shared__ float red[4];
  const int tid = threadIdx.x;
  const int blk = blockIdx.x;

  if (blk < 128) {
    // ---- csd[b][k] = (1/(256*sqrt(512))) * DFT_t( autocorr(s)[t-255] )
    const int bb = blk;
    for (int t = tid; t < 768; t += 256) {
      float v = 0.f;
      if (t < 512) {
        const float4* xp = (const float4*)(x + (bb * 512 + t) * 16);
        float4 a = xp[0], b = xp[1], c = xp[2], d = xp[3];
        v = a.x + a.y + a.z + a.w + b.x + b.y + b.z + b.w +
            c.x + c.y + c.z + c.w + d.x + d.y + d.z + d.w;
      }
      sl[t] = v;
    }
    __syncthreads();
    {
      float a0 = 0.f, a1 = 0.f, a2 = 0.f, a3 = 0.f;
      for (int tau = 0; tau < 512; tau += 4) {
        float4 u = *(const float4*)&sl[tau];
        a0 = fmaf(u.x, sl[tau + tid], a0);
        a1 = fmaf(u.y, sl[tau + tid + 1], a1);
        a2 = fmaf(u.z, sl[tau + tid + 2], a2);
        a3 = fmaf(u.w, sl[tau + tid + 3], a3);
      }
      ac[tid] = (a0 + a1) + (a2 + a3);
    }
    {
      float p = sl[tid] * sl[tid + 256];
#pragma unroll
      for (int off = 32; off; off >>= 1) p += __shfl_down(p, off);
      if ((tid & 63) == 0) red[tid >> 6] = p;
    }
    __syncthreads();
    if (tid == 0) ac[256] = red[0] + red[1] + red[2] + red[3];
    __syncthreads();
    const float S1 = SORTHO / 256.f;
    const int k = tid;            // 0..255; k=256 via exact alternating chain
    float sth, cth;
    __sincosf((float)k * 0.01227184630f, &sth, &cth);
    float c = 1.f, s = 0.f, re = 0.f, im = 0.f;
    float re256 = 0.f, sg = 1.f;
    for (int t = 0; t < 512; ++t) {
      int d = t - 255;
      float ov = ac[d < 0 ? -d : d];
      re = fmaf(ov, c, re);
      im = fmaf(-ov, s, im);
      re256 = fmaf(ov, sg, re256);
      sg = -sg;
      float nc = fmaf(c, cth, -s * sth);
      s = fmaf(s, cth, c * sth);
      c = nc;
    }
    *(float2*)(csd + (bb * NF_ + k) * 2) = make_float2(re * S1, im * S1);
    if (tid == 0)
      *(float2*)(csd + (bb * NF_ + 256) * 2) = make_float2(re256 * S1, 0.f);
    return;
  }

  if (blk < 2698) {
    // ---- W_gate (16448 x 257 f32) -> Bfrag bf16 fragment-major.
    const int slot = (blk - 128) * 256 + tid;          // < 657920
    const int nblk = slot / 32896;                     // 514*64
    const int rem = slot - nblk * 32896;
    const int kb = rem >> 6, lane = rem & 63;
    const int n = nblk * 16 + (lane & 15);
    const int k0 = kb * 32 + (lane >> 4) * 8;
    unsigned int w[4];
#pragma unroll
    for (int jp = 0; jp < 4; ++jp) {
      float v0 = (n < NF_) ? Wg[(k0 + jp * 2) * NF_ + n] : 0.f;
      float v1 = (n < NF_) ? Wg[(k0 + jp * 2 + 1) * NF_ + n] : 0.f;
      w[jp] = f2bf(v0) | (f2bf(v1) << 16);
    }
    *(uint4*)(Bf + (size_t)slot * 8) = make_uint4(w[0], w[1], w[2], w[3]);
    return;
  }

  if (blk < 2834) {
    // ---- rfft twiddle table, fragment-major, S folded.
    const int slot = (blk - 2698) * 256 + tid;   // < 34816
    const int tile = slot >> 10, rem = slot & 1023;
    const int ks = rem >> 6, quad = (rem >> 4) & 3, l15 = rem & 15;
    const int grow = tile * 16 + l15;
    unsigned int pk[4];
#pragma unroll
    for (int jp = 0; jp < 4; ++jp) {
      float v0 = 0.f, v1 = 0.f;
      if (grow < 514) {
        const int k = grow >> 1;
        const int t0 = ks * 32 + quad * 8 + jp * 2;
        float s0, c0, s1, c1;
        __sincosf((float)((k * t0) & 511) * 0.01227184630f, &s0, &c0);
        __sincosf((float)((k * (t0 + 1)) & 511) * 0.01227184630f, &s1, &c1);
        v0 = (grow & 1) ? -s0 * SORTHO : c0 * SORTHO;
        v1 = (grow & 1) ? -s1 * SORTHO : c1 * SORTHO;
      }
      pk[jp] = f2bf(v0) | (f2bf(v1) << 16);
    }
    *(uint4*)(TWf + slot * 8) = make_uint4(pk[0], pk[1], pk[2], pk[3]);
    return;
  }

  {
    // ---- irfft twiddle table, fragment-major, S + Hermitian folded.
    const int slot = (blk - 2834) * 256 + tid;   // < 34816
    const int tile = slot / 1088, rem = slot % 1088;
    const int ks = rem >> 6, sub = rem & 63;
    const int quad = sub >> 4, l15 = sub & 15;
    const int t = tile * 16 + l15;
    unsigned int pk[4];
#pragma unroll
    for (int jp = 0; jp < 4; ++jp) {
      float v0 = 0.f, v1 = 0.f;
#pragma unroll
      for (int h = 0; h < 2; ++h) {
        const int kidx = ks * 32 + quad * 8 + jp * 2 + h;
        float v = 0.f;
        if (kidx < 514) {
          const int k = kidx >> 1;
          const float hw = (k == 0 || k == 256) ? SORTHO : 2.f * SORTHO;
          float s, c;
          __sincosf((float)((k * t) & 511) * 0.01227184630f, &s, &c);
          v = (kidx & 1) ? -s * hw : c * hw;
        }
        if (h == 0) v0 = v; else v1 = v;
      }
      pk[jp] = f2bf(v0) | (f2bf(v1) << 16);
    }
    *(uint4*)(ITWf + slot * 8) = make_uint4(pk[0], pk[1], pk[2], pk[3]);
  }
}

// ---------- K3: rfft GEMM: fftc = TWf x X^T + csd. grid (2,128) x 512 thr.
__global__ __launch_bounds__(512) void k_fftg(const float* __restrict__ x,
                                              const unsigned short* __restrict__ TWf,
                                              const float* __restrict__ csd,
                                              float* __restrict__ fftc) {
  __shared__ __align__(16) unsigned short Xs[16 * 512];
  const int tid = threadIdx.x, mh = blockIdx.x, bb = blockIdx.y;
#pragma unroll
  for (int it = 0; it < 16; ++it) {
    int e = it * 512 + tid;
    int f = e & 15, t = e >> 4;
    float val = x[(bb * 512 + t) * 16 + f];
    Xs[f * 512 + (((t >> 3) ^ (f & 7)) * 8) + (t & 7)] = (unsigned short)f2bf(val);
  }
  __syncthreads();
  const int lane = tid & 63, wave = tid >> 6;   // 8 waves
  const int l15 = lane & 15, quad = lane >> 4;
  floatx4 acc0 = {0,0,0,0}, acc1 = {0,0,0,0}, acc2 = {0,0,0,0};
  const int g0 = mh * 17 + wave, g1 = g0 + 8, g2 = mh * 17 + 16;
#pragma unroll
  for (int ks = 0; ks < 16; ++ks) {
    short8 bf = *(const short8*)&Xs[l15 * 512 + (((ks * 4 + quad) ^ (l15 & 7)) * 8)];
    short8 af0 = *(const short8*)(TWf + g0 * 8192 + ks * 512 + quad * 128 + l15 * 8);
    short8 af1 = *(const short8*)(TWf + g1 * 8192 + ks * 512 + quad * 128 + l15 * 8);
    acc0 = __builtin_amdgcn_mfma_f32_16x16x32_bf16(af0, bf, acc0, 0, 0, 0);
    acc1 = __builtin_amdgcn_mfma_f32_16x16x32_bf16(af1, bf, acc1, 0, 0, 0);
    if (wave == 0) {
      short8 af2 = *(const short8*)(TWf + g2 * 8192 + ks * 512 + quad * 128 + l15 * 8);
      acc2 = __builtin_amdgcn_mfma_f32_16x16x32_bf16(af2, bf, acc2, 0, 0, 0);
    }
  }
#pragma unroll
  for (int i = 0; i < 3; ++i) {
    if (i == 2 && wave != 0) break;
    const int g = (i == 0) ? g0 : (i == 1) ? g1 : g2;
    floatx4 a = (i == 0) ? acc0 : (i == 1) ? acc1 : acc2;
#pragma unroll
    for (int r = 0; r < 4; ++r) {
      const int grow = g * 16 + quad * 4 + r;
      if (grow < 514) {
        const int k = grow >> 1, ri = grow & 1;
        fftc[((bb * NF_ + k) * 16 + l15) * 2 + ri] =
            a[r] + csd[(bb * NF_ + k) * 2 + ri];
      }
    }
  }
}

// ---------- K4: new_fft only (proj recomputed in-thread; NO Afrag write).
// grid 2056 x 256 thr.
__global__ __launch_bounds__(256) void k_new(const float* __restrict__ fftc,
                                             const float* __restrict__ W_proj,
                                             const float* __restrict__ b_proj,
                                             const float* __restrict__ mag_w,
                                             const float* __restrict__ mag_b,
                                             const float* __restrict__ phase_w,
                                             const float* __restrict__ phase_b,
                                             float* __restrict__ nf) {
  __shared__ float wp[256], bp[64];
  const int tid = threadIdx.x;
  wp[tid] = W_proj[tid];
  if (tid < 64) bp[tid] = b_proj[tid];
  __syncthreads();
  const int idx = blockIdx.x * 256 + tid;
  const int bn = idx >> 4;
  const int n = bn % NF_;
  float2 z = *(const float2*)(fftc + idx * 2);
  float d = z.x * z.x + z.y * z.y;
  float ir = d > 0.f ? rsqrtf(d) : 0.f;
  float mag = d * ir;
  float sn = z.y * ir;
  float cs = d > 0.f ? z.x * ir : 1.f;
  float fr = (float)n * 0.1953125f;  // 100/512
  float am = 0.f, ap = 0.f;
#pragma unroll 8
  for (int h = 0; h < 64; ++h) {
    float p = fmaf(mag, wp[h], fmaf(sn, wp[64 + h], fmaf(cs, wp[128 + h],
              fmaf(fr, wp[192 + h], bp[h]))));
    p = fmaxf(p, 0.f);
    am = fmaf(p, mag_w[n * 64 + h], am);
    ap = fmaf(p, phase_w[n * 64 + h], ap);
  }
  float m = fmaxf(am + mag_b[n], 0.f);
  float ph = 6.28318530718f / (1.f + __expf(-(ap + phase_b[n])));
  float sp, cp;
  __sincosf(ph, &sp, &cp);
  *(float2*)(nf + idx * 2) = make_float2(m * cp, m * sp);
}

// ---------- K5: gate GEMM, proj computed in-kernel (fused k_new staging).
// grid (16 sp, 32 mgg) x 256. Per step (= one n): each staging thread computes
// its 16 proj values from fftc (2 float2 loads + VALU) and writes the same
// LDS chunks as v14; barrier structure unchanged. B direct->reg prefetch.
__global__ __launch_bounds__(256, 2) void k_gemm(const float* __restrict__ fftc,
                                                 const float* __restrict__ W_proj,
                                                 const float* __restrict__ b_proj,
                                                 const unsigned short* __restrict__ Bf,
                                                 unsigned short* __restrict__ gpart) {
  __shared__ __align__(16) unsigned short As[2][4096];  // [buf][(kf*4+mi)*512 + lane*8]
  const int tid = threadIdx.x;
  const int sp = blockIdx.x, mgg = blockIdx.y;
  const int lane = tid & 63, wv = tid >> 6;
  const int q = lane >> 4, l15 = lane & 15;
  const int p0 = (NF_ * sp) >> 4, p1 = (NF_ * (sp + 1)) >> 4;
  const int nsteps = p1 - p0;                 // 16 or 17 (one n per step)
  const int c0 = wv * 2, c1 = c0 + 1;         // LDS chunk = kf*4 + mi
  const int kf = wv >> 1;                     // h-half this wave stages
  const int mi0 = (wv & 1) * 2, mi1 = mi0 + 1;
  const int b0 = mgg * 4 + mi0, b1 = b0 + 1;  // global batch rows staged

  // per-thread W_proj slice for its 8 h values (h = kf*32 + q*8 + j)
  float4 w4[8]; float bpv[8];
  const int hb = kf * 32 + q * 8;
#pragma unroll
  for (int j = 0; j < 8; ++j) {
    const int h = hb + j;
    w4[j] = make_float4(W_proj[h], W_proj[64 + h], W_proj[128 + h], W_proj[192 + h]);
    bpv[j] = b_proj[h];
  }

  const unsigned short* pb = Bf + (size_t)(wv * 5) * FRAGS
                             + (size_t)(p0 * 2) * 512 + lane * 8;

  floatx4 acc[4][5];
#pragma unroll
  for (int mi = 0; mi < 4; ++mi)
#pragma unroll
    for (int nn = 0; nn < 5; ++nn) acc[mi][nn] = (floatx4){0.f, 0.f, 0.f, 0.f};

  float2 z0 = *(const float2*)(fftc + ((b0 * NF_ + p0) * 16 + l15) * 2);
  float2 z1 = *(const float2*)(fftc + ((b1 * NF_ + p0) * 16 + l15) * 2);
  short8 bX[5], bY[5];
#pragma unroll
  for (int nn = 0; nn < 5; ++nn) {
    bX[nn] = *(const short8*)(pb + (size_t)nn * FRAGS);
    bY[nn] = *(const short8*)(pb + (size_t)nn * FRAGS + 512);
  }

  for (int s = 0; s < nsteps; ++s) {
    const int n = p0 + s;
    const float fr = (float)n * 0.1953125f;
    // issue next-step z loads early (hide latency under proj VALU + MFMA)
    float2 zn0, zn1;
    if (s + 1 < nsteps) {
      zn0 = *(const float2*)(fftc + ((b0 * NF_ + n + 1) * 16 + l15) * 2);
      zn1 = *(const float2*)(fftc + ((b1 * NF_ + n + 1) * 16 + l15) * 2);
    }
    unsigned short* dst = &As[s & 1][0];
    {
      float d = z0.x * z0.x + z0.y * z0.y;
      float ir = d > 0.f ? rsqrtf(d) : 0.f;
      float mag = d * ir, sn = z0.y * ir;
      float cs = d > 0.f ? z0.x * ir : 1.f;
      unsigned int w[4];
#pragma unroll
      for (int j = 0; j < 8; ++j) {
        float p = fmaf(mag, w4[j].x, fmaf(sn, w4[j].y, fmaf(cs, w4[j].z,
                  fmaf(fr, w4[j].w, bpv[j]))));
        p = fmaxf(p, 0.f);
        unsigned int pb16 = f2bf(p);
        if (j & 1) w[j >> 1] |= pb16 << 16; else w[j >> 1] = pb16;
      }
      *(uint4*)(dst + c0 * 512 + lane * 8) = make_uint4(w[0], w[1], w[2], w[3]);
    }
    {
      float d = z1.x * z1.x + z1.y * z1.y;
      float ir = d > 0.f ? rsqrtf(d) : 0.f;
      float mag = d * ir, sn = z1.y * ir;
      float cs = d > 0.f ? z1.x * ir : 1.f;
      unsigned int w[4];
#pragma unroll
      for (int j = 0; j < 8; ++j) {
        float p = fmaf(mag, w4[j].x, fmaf(sn, w4[j].y, fmaf(cs, w4[j].z,
                  fmaf(fr, w4[j].w, bpv[j]))));
        p = fmaxf(p, 0.f);
        unsigned int pb16 = f2bf(p);
        if (j & 1) w[j >> 1] |= pb16 << 16; else w[j >> 1] = pb16;
      }
      *(uint4*)(dst + c1 * 512 + lane * 8) = make_uint4(w[0], w[1], w[2], w[3]);
    }
    z0 = zn0; z1 = zn1;
    __builtin_amdgcn_sched_barrier(0);
    asm volatile("s_waitcnt lgkmcnt(0)" ::: "memory");
    __builtin_amdgcn_s_barrier();
    __builtin_amdgcn_sched_barrier(0);
    const unsigned short* rb = &As[s & 1][0];
    {
      short8 a0 = *(const short8*)(rb + 0 * 512 + lane * 8);
      short8 a1 = *(const short8*)(rb + 1 * 512 + lane * 8);
      short8 a2 = *(const short8*)(rb + 2 * 512 + lane * 8);
      short8 a3 = *(const short8*)(rb + 3 * 512 + lane * 8);
#pragma unroll
      for (int nn = 0; nn < 5; ++nn) {
        acc[0][nn] = __builtin_amdgcn_mfma_f32_16x16x32_bf16(a0, bX[nn], acc[0][nn], 0, 0, 0);
        acc[1][nn] = __builtin_amdgcn_mfma_f32_16x16x32_bf16(a1, bX[nn], acc[1][nn], 0, 0, 0);
        acc[2][nn] = __builtin_amdgcn_mfma_f32_16x16x32_bf16(a2, bX[nn], acc[2][nn], 0, 0, 0);
        acc[3][nn] = __builtin_amdgcn_mfma_f32_16x16x32_bf16(a3, bX[nn], acc[3][nn], 0, 0, 0);
      }
      if (s + 1 < nsteps) {
#pragma unroll
        for (int nn = 0; nn < 5; ++nn)
          bX[nn] = *(const short8*)(pb + (size_t)nn * FRAGS + 1024);
      }
    }
    {
      short8 a0 = *(const short8*)(rb + 4 * 512 + lane * 8);
      short8 a1 = *(const short8*)(rb + 5 * 512 + lane * 8);
      short8 a2 = *(const short8*)(rb + 6 * 512 + lane * 8);
      short8 a3 = *(const short8*)(rb + 7 * 512 + lane * 8);
#pragma unroll
      for (int nn = 0; nn < 5; ++nn) {
        acc[0][nn] = __builtin_amdgcn_mfma_f32_16x16x32_bf16(a0, bY[nn], acc[0][nn], 0, 0, 0);
        acc[1][nn] = __builtin_amdgcn_mfma_f32_16x16x32_bf16(a1, bY[nn], acc[1][nn], 0, 0, 0);
        acc[2][nn] = __builtin_amdgcn_mfma_f32_16x16x32_bf16(a2, bY[nn], acc[2][nn], 0, 0, 0);
        acc[3][nn] = __builtin_amdgcn_mfma_f32_16x16x32_bf16(a3, bY[nn], acc[3][nn], 0, 0, 0);
      }
      if (s + 1 < nsteps) {
#pragma unroll
        for (int nn = 0; nn < 5; ++nn)
          bY[nn] = *(const short8*)(pb + (size_t)nn * FRAGS + 1536);
        pb += 1024;
      }
    }
  }

  // fragment-major partial store: coalesced 8B/lane.
#pragma unroll
  for (int mi = 0; mi < 4; ++mi)
#pragma unroll
    for (int nn = 0; nn < 5; ++nn) {
      unsigned int lo = f2bf(acc[mi][nn][0]) | (f2bf(acc[mi][nn][1]) << 16);
      unsigned int hi = f2bf(acc[mi][nn][2]) | (f2bf(acc[mi][nn][3]) << 16);
      *(uint2*)(gpart + ((((size_t)sp * 128 + mgg * 4 + mi) * 20) + wv * 5 + nn) * 256
                + lane * 4) = make_uint2(lo, hi);
    }
}

// ---------- K6: irfft GEMM + fused split-K w-reduction (depth SPK=16).
// grid (2,128) x 512 thr. out = LN(ITWf x WF^T + x).
__global__ __launch_bounds__(512) void k_recong(const float* __restrict__ fftc,
                                                const float* __restrict__ nfb,
                                                const unsigned short* __restrict__ gpart,
                                                const float* __restrict__ b_gate,
                                                const unsigned short* __restrict__ ITWf,
                                                const float* __restrict__ x,
                                                const float* __restrict__ ln_g,
                                                const float* __restrict__ ln_b,
                                                float* __restrict__ out) {
  __shared__ __align__(16) unsigned short WFs[16 * 576];
  __shared__ float wls[16 * 257];
  const int tid = threadIdx.x, th = blockIdx.x, bb = blockIdx.y;
  // fused w-reduction: sum SPK partials from gpart fragment layout.
  const unsigned short* gpb = gpart + (size_t)bb * 5120;   // mfrag = bb
  for (int t = tid; t < 1088; t += 512) {
    const int n = ((t >> 6) << 4) + (t & 15);
    if (n < NF_) {
      const int quad = (t >> 4) & 3;
      const float bg = b_gate[n];
      float g0 = bg, g1 = bg, g2 = bg, g3 = bg;
#pragma unroll
      for (int s2 = 0; s2 < SPK; ++s2) {
        uint2 v = *(const uint2*)(gpb + (size_t)s2 * 655360 + (size_t)t * 4);
        g0 += bf2f(v.x & 0xFFFFu); g1 += bf2f(v.x >> 16);
        g2 += bf2f(v.y & 0xFFFFu); g3 += bf2f(v.y >> 16);
      }
      float gv[4] = {g0, g1, g2, g3};
#pragma unroll
      for (int r = 0; r < 4; ++r) {
        float g = gv[r];
        float sg = 1.f / (1.f + __expf(-g));
        float gs = g * sg;
        wls[(quad * 4 + r) * 257 + n] = 1.f / (1.f + __expf(-gs));
      }
    }
  }
  __syncthreads();
#pragma unroll
  for (int it = 0; it < 17; ++it) {
    int e = it * 512 + tid;        // < 8704 = 16*544
    int f = e & 15, row = e >> 4;
    float val = 0.f;
    if (row < 514) {
      int k = row >> 1, ri = row & 1;
      int base = ((bb * NF_ + k) * 16 + f) * 2 + ri;
      float fz = fftc[base], nz = nfb[base];
      float wv = wls[f * 257 + k];
      val = fz + wv * (nz - fz);
    }
    WFs[f * 576 + (((row >> 3) ^ (f & 7)) * 8) + (row & 7)] = (unsigned short)f2bf(val);
  }
  __syncthreads();
  const int lane = tid & 63, wave = tid >> 6;   // 8 waves x 2 tiles
  const int l15 = lane & 15, quad = lane >> 4;
  const float gg = ln_g[l15], gb = ln_b[l15];
  floatx4 acc[2];
  acc[0] = (floatx4){0.f, 0.f, 0.f, 0.f};
  acc[1] = (floatx4){0.f, 0.f, 0.f, 0.f};
  const int tg0 = th * 16 + wave, tg1 = tg0 + 8;
#pragma unroll
  for (int ks = 0; ks < 17; ++ks) {
    short8 bf = *(const short8*)&WFs[l15 * 576 + (((ks * 4 + quad) ^ (l15 & 7)) * 8)];
    short8 af0 = *(const short8*)(ITWf + tg0 * 8704 + ks * 512 + quad * 128 + l15 * 8);
    short8 af1 = *(const short8*)(ITWf + tg1 * 8704 + ks * 512 + quad * 128 + l15 * 8);
    acc[0] = __builtin_amdgcn_mfma_f32_16x16x32_bf16(af0, bf, acc[0], 0, 0, 0);
    acc[1] = __builtin_amdgcn_mfma_f32_16x16x32_bf16(af1, bf, acc[1], 0, 0, 0);
  }
#pragma unroll
  for (int i = 0; i < 2; ++i) {
    const int tg = (i == 0) ? tg0 : tg1;
#pragma unroll
    for (int r = 0; r < 4; ++r) {
      const int t = tg * 16 + quad * 4 + r;
      float y = acc[i][r] + x[(bb * 512 + t) * 16 + l15];
      float s1 = y, s2 = y * y;
#pragma unroll
      for (int m = 1; m < 16; m <<= 1) {
        s1 += __shfl_xor(s1, m);
        s2 += __shfl_xor(s2, m);
      }
      float mu = s1 * 0.0625f;
      float var = s2 * 0.0625f - mu * mu;
      float rs = rsqrtf(var + 1e-5f);
      out[(bb * 512 + t) * 16 + l15] = (y - mu) * rs * gg + gb;
    }
  }
}

extern "C" void kernel_launch(void* const* d_in, const int* in_sizes, int n_in,
                              void* d_out, int out_size, void* d_ws, size_t ws_size,
                              hipStream_t stream) {
  const float* x = (const float*)d_in[0];
  const float* W_proj = (const float*)d_in[1];
  const float* b_proj = (const float*)d_in[2];
  const float* W_gate = (const float*)d_in[3];
  const float* b_gate = (const float*)d_in[4];
  const float* mag_w = (const float*)d_in[5];
  const float* mag_b = (const float*)d_in[6];
  const float* phase_w = (const float*)d_in[7];
  const float* phase_b = (const float*)d_in[8];
  const float* ln_g = (const float*)d_in[9];
  const float* ln_b = (const float*)d_in[10];
  float* out = (float*)d_out;
  float* ws = (float*)d_ws;

  // workspace (float slots)
  float* fftc = ws;                                          // 1,052,672 f
  float* nfb = ws + 1052672;                                 // 1,052,672 f
  float* csd = ws + 2631680;                                 //    65,792 f
  unsigned short* Bfrag = (unsigned short*)(ws + 2697472);   //  5,263,360 sh (10.5 MB)
  unsigned short* gpart = (unsigned short*)(ws + 5329152);   // 10,485,760 sh (21.0 MB)
  unsigned short* TWf = (unsigned short*)(ws + 10572032);    //    278,528 sh
  unsigned short* ITWf = (unsigned short*)(ws + 10711296);   //    278,528 sh

  hipLaunchKernelGGL(k_prep, dim3(2970), dim3(256), 0, stream,
                     x, W_gate, csd, Bfrag, TWf, ITWf);
  hipLaunchKernelGGL(k_fftg, dim3(2, 128), dim3(512), 0, stream, x, TWf, csd, fftc);
  hipLaunchKernelGGL(k_gemm, dim3(16, 32), dim3(256), 0, stream, fftc, W_proj,
                     b_proj, Bfrag, gpart);
  hipLaunchKernelGGL(k_new, dim3(2056), dim3(256), 0, stream, fftc, W_proj, b_proj,
                     mag_w, mag_b, phase_w, phase_b, nfb);
  hipLaunchKernelGGL(k_recong, dim3(2, 128), dim3(512), 0, stream, fftc, nfb, gpart,
                     b_gate, ITWf, x, ln_g, ln_b, out);
}

// Round 10
// 178.218 us; speedup vs baseline: 1.0982x; 1.0176x over previous
//
#include <hip/hip_runtime.h>

// AdaptiveSpectrumLayer: B=128, H=T=512, F=16, NF=257
// v16: v15 + k_new fused into k_fftg (-> k_spec). v12 proved the fused epilogue
//      math; its +17 µs cost was the 74 MB Afrag write, which v15 eliminated.
//      4 launches: prep -> spec -> gemm -> recong. Everything else = v15.

#define NF_ 257
#define FRAGS 263168     // NKB*512 shorts: stride between n-blocks in Bfrag
#define SPK 16
#define SORTHO 0.04419417382f   // 1/sqrt(512)

typedef __attribute__((ext_vector_type(8))) short short8;
typedef __attribute__((ext_vector_type(4))) float floatx4;

__device__ __forceinline__ unsigned int f2bf(float x) {
  union { float f; unsigned int u; } v; v.f = x;
  return (v.u + 0x7FFFu + ((v.u >> 16) & 1u)) >> 16;
}
__device__ __forceinline__ float bf2f(unsigned int u16) {
  union { unsigned int u; float f; } v; v.u = u16 << 16;
  return v.f;
}

// ---------- K_prep: fused {csd | wgt | tw | itw} by blockIdx range.
// blocks [0,128): csd; [128,2698): wgt; [2698,2834): tw; [2834,2970): itw.
__global__ __launch_bounds__(256) void k_prep(const float* __restrict__ x,
                                              const float* __restrict__ Wg,
                                              float* __restrict__ csd,
                                              unsigned short* __restrict__ Bf,
                                              unsigned short* __restrict__ TWf,
                                              unsigned short* __restrict__ ITWf) {
  __shared__ float sl[768];
  __shared__ float ac[257];
  __shared__ float red[4];
  const int tid = threadIdx.x;
  const int blk = blockIdx.x;

  if (blk < 128) {
    // ---- csd[b][k] = (1/(256*sqrt(512))) * DFT_t( autocorr(s)[t-255] )
    const int bb = blk;
    for (int t = tid; t < 768; t += 256) {
      float v = 0.f;
      if (t < 512) {
        const float4* xp = (const float4*)(x + (bb * 512 + t) * 16);
        float4 a = xp[0], b = xp[1], c = xp[2], d = xp[3];
        v = a.x + a.y + a.z + a.w + b.x + b.y + b.z + b.w +
            c.x + c.y + c.z + c.w + d.x + d.y + d.z + d.w;
      }
      sl[t] = v;
    }
    __syncthreads();
    {
      float a0 = 0.f, a1 = 0.f, a2 = 0.f, a3 = 0.f;
      for (int tau = 0; tau < 512; tau += 4) {
        float4 u = *(const float4*)&sl[tau];
        a0 = fmaf(u.x, sl[tau + tid], a0);
        a1 = fmaf(u.y, sl[tau + tid + 1], a1);
        a2 = fmaf(u.z, sl[tau + tid + 2], a2);
        a3 = fmaf(u.w, sl[tau + tid + 3], a3);
      }
      ac[tid] = (a0 + a1) + (a2 + a3);
    }
    {
      float p = sl[tid] * sl[tid + 256];
#pragma unroll
      for (int off = 32; off; off >>= 1) p += __shfl_down(p, off);
      if ((tid & 63) == 0) red[tid >> 6] = p;
    }
    __syncthreads();
    if (tid == 0) ac[256] = red[0] + red[1] + red[2] + red[3];
    __syncthreads();
    const float S1 = SORTHO / 256.f;
    const int k = tid;            // 0..255; k=256 via exact alternating chain
    float sth, cth;
    __sincosf((float)k * 0.01227184630f, &sth, &cth);
    float c = 1.f, s = 0.f, re = 0.f, im = 0.f;
    float re256 = 0.f, sg = 1.f;
    for (int t = 0; t < 512; ++t) {
      int d = t - 255;
      float ov = ac[d < 0 ? -d : d];
      re = fmaf(ov, c, re);
      im = fmaf(-ov, s, im);
      re256 = fmaf(ov, sg, re256);
      sg = -sg;
      float nc = fmaf(c, cth, -s * sth);
      s = fmaf(s, cth, c * sth);
      c = nc;
    }
    *(float2*)(csd + (bb * NF_ + k) * 2) = make_float2(re * S1, im * S1);
    if (tid == 0)
      *(float2*)(csd + (bb * NF_ + 256) * 2) = make_float2(re256 * S1, 0.f);
    return;
  }

  if (blk < 2698) {
    // ---- W_gate (16448 x 257 f32) -> Bfrag bf16 fragment-major.
    const int slot = (blk - 128) * 256 + tid;          // < 657920
    const int nblk = slot / 32896;                     // 514*64
    const int rem = slot - nblk * 32896;
    const int kb = rem >> 6, lane = rem & 63;
    const int n = nblk * 16 + (lane & 15);
    const int k0 = kb * 32 + (lane >> 4) * 8;
    unsigned int w[4];
#pragma unroll
    for (int jp = 0; jp < 4; ++jp) {
      float v0 = (n < NF_) ? Wg[(k0 + jp * 2) * NF_ + n] : 0.f;
      float v1 = (n < NF_) ? Wg[(k0 + jp * 2 + 1) * NF_ + n] : 0.f;
      w[jp] = f2bf(v0) | (f2bf(v1) << 16);
    }
    *(uint4*)(Bf + (size_t)slot * 8) = make_uint4(w[0], w[1], w[2], w[3]);
    return;
  }

  if (blk < 2834) {
    // ---- rfft twiddle table, fragment-major, S folded.
    const int slot = (blk - 2698) * 256 + tid;   // < 34816
    const int tile = slot >> 10, rem = slot & 1023;
    const int ks = rem >> 6, quad = (rem >> 4) & 3, l15 = rem & 15;
    const int grow = tile * 16 + l15;
    unsigned int pk[4];
#pragma unroll
    for (int jp = 0; jp < 4; ++jp) {
      float v0 = 0.f, v1 = 0.f;
      if (grow < 514) {
        const int k = grow >> 1;
        const int t0 = ks * 32 + quad * 8 + jp * 2;
        float s0, c0, s1, c1;
        __sincosf((float)((k * t0) & 511) * 0.01227184630f, &s0, &c0);
        __sincosf((float)((k * (t0 + 1)) & 511) * 0.01227184630f, &s1, &c1);
        v0 = (grow & 1) ? -s0 * SORTHO : c0 * SORTHO;
        v1 = (grow & 1) ? -s1 * SORTHO : c1 * SORTHO;
      }
      pk[jp] = f2bf(v0) | (f2bf(v1) << 16);
    }
    *(uint4*)(TWf + slot * 8) = make_uint4(pk[0], pk[1], pk[2], pk[3]);
    return;
  }

  {
    // ---- irfft twiddle table, fragment-major, S + Hermitian folded.
    const int slot = (blk - 2834) * 256 + tid;   // < 34816
    const int tile = slot / 1088, rem = slot % 1088;
    const int ks = rem >> 6, sub = rem & 63;
    const int quad = sub >> 4, l15 = sub & 15;
    const int t = tile * 16 + l15;
    unsigned int pk[4];
#pragma unroll
    for (int jp = 0; jp < 4; ++jp) {
      float v0 = 0.f, v1 = 0.f;
#pragma unroll
      for (int h = 0; h < 2; ++h) {
        const int kidx = ks * 32 + quad * 8 + jp * 2 + h;
        float v = 0.f;
        if (kidx < 514) {
          const int k = kidx >> 1;
          const float hw = (k == 0 || k == 256) ? SORTHO : 2.f * SORTHO;
          float s, c;
          __sincosf((float)((k * t) & 511) * 0.01227184630f, &s, &c);
          v = (kidx & 1) ? -s * hw : c * hw;
        }
        if (h == 0) v0 = v; else v1 = v;
      }
      pk[jp] = f2bf(v0) | (f2bf(v1) << 16);
    }
    *(uint4*)(ITWf + slot * 8) = make_uint4(pk[0], pk[1], pk[2], pk[3]);
  }
}

// ---------- K_spec: rfft GEMM + fused new_fft (NO Afrag -- v12 epilogue minus
// the Afrag stores). grid (2,128) x 512 thr.
__global__ __launch_bounds__(512) void k_spec(const float* __restrict__ x,
                                              const unsigned short* __restrict__ TWf,
                                              const float* __restrict__ csd,
                                              const float* __restrict__ W_proj,
                                              const float* __restrict__ b_proj,
                                              const float* __restrict__ mag_w,
                                              const float* __restrict__ mag_b,
                                              const float* __restrict__ phase_w,
                                              const float* __restrict__ phase_b,
                                              float* __restrict__ fftc,
                                              float* __restrict__ nf) {
  __shared__ __align__(16) unsigned short Xs[16 * 512];
  __shared__ float4 wp4[64];
  __shared__ float bps[64];
  const int tid = threadIdx.x, mh = blockIdx.x, bb = blockIdx.y;
  if (tid < 64) {
    wp4[tid] = make_float4(W_proj[tid], W_proj[64 + tid], W_proj[128 + tid],
                           W_proj[192 + tid]);
    bps[tid] = b_proj[tid];
  }
#pragma unroll
  for (int it = 0; it < 16; ++it) {
    int e = it * 512 + tid;
    int f = e & 15, t = e >> 4;
    float val = x[(bb * 512 + t) * 16 + f];
    Xs[f * 512 + (((t >> 3) ^ (f & 7)) * 8) + (t & 7)] = (unsigned short)f2bf(val);
  }
  __syncthreads();
  const int lane = tid & 63, wave = tid >> 6;   // 8 waves
  const int l15 = lane & 15, quad = lane >> 4;
  floatx4 acc0 = {0,0,0,0}, acc1 = {0,0,0,0}, acc2 = {0,0,0,0};
  const int g0 = mh * 17 + wave, g1 = g0 + 8, g2 = mh * 17 + 16;
#pragma unroll
  for (int ks = 0; ks < 16; ++ks) {
    short8 bf = *(const short8*)&Xs[l15 * 512 + (((ks * 4 + quad) ^ (l15 & 7)) * 8)];
    short8 af0 = *(const short8*)(TWf + g0 * 8192 + ks * 512 + quad * 128 + l15 * 8);
    short8 af1 = *(const short8*)(TWf + g1 * 8192 + ks * 512 + quad * 128 + l15 * 8);
    acc0 = __builtin_amdgcn_mfma_f32_16x16x32_bf16(af0, bf, acc0, 0, 0, 0);
    acc1 = __builtin_amdgcn_mfma_f32_16x16x32_bf16(af1, bf, acc1, 0, 0, 0);
    if (wave == 0) {
      short8 af2 = *(const short8*)(TWf + g2 * 8192 + ks * 512 + quad * 128 + l15 * 8);
      acc2 = __builtin_amdgcn_mfma_f32_16x16x32_bf16(af2, bf, acc2, 0, 0, 0);
    }
  }
#pragma unroll
  for (int i = 0; i < 3; ++i) {
    if (i == 2 && wave != 0) break;
    const int g = (i == 0) ? g0 : (i == 1) ? g1 : g2;
    floatx4 a = (i == 0) ? acc0 : (i == 1) ? acc1 : acc2;
#pragma unroll
    for (int kp = 0; kp < 2; ++kp) {
      const int grow = g * 16 + quad * 4 + kp * 2;   // even; pair (re,im)
      if (grow < 514) {
        const int k = grow >> 1;
        float2 cz = *(const float2*)(csd + (bb * NF_ + k) * 2);
        float re = a[kp * 2] + cz.x;
        float im = a[kp * 2 + 1] + cz.y;
        const int ofc = ((bb * NF_ + k) * 16 + l15) * 2;
        *(float2*)(fftc + ofc) = make_float2(re, im);
        // fused k_new element work (no Afrag store)
        float d = re * re + im * im;
        float ir = d > 0.f ? rsqrtf(d) : 0.f;
        float mag = d * ir;
        float sn = im * ir;
        float cs = d > 0.f ? re * ir : 1.f;
        float fr = (float)k * 0.1953125f;   // 100/512
        float am = 0.f, ap = 0.f;
        const float4* mwp = (const float4*)(mag_w + k * 64);
        const float4* pwp = (const float4*)(phase_w + k * 64);
#pragma unroll
        for (int hg = 0; hg < 8; ++hg) {
          float4 mw0 = mwp[hg * 2], mw1 = mwp[hg * 2 + 1];
          float4 pw0 = pwp[hg * 2], pw1 = pwp[hg * 2 + 1];
#pragma unroll
          for (int j = 0; j < 8; ++j) {
            const int h = hg * 8 + j;
            float4 wv = wp4[h];
            float p = fmaf(mag, wv.x, fmaf(sn, wv.y, fmaf(cs, wv.z,
                      fmaf(fr, wv.w, bps[h]))));
            p = fmaxf(p, 0.f);
            float mwj = (j < 4) ? (&mw0.x)[j] : (&mw1.x)[j - 4];
            float pwj = (j < 4) ? (&pw0.x)[j] : (&pw1.x)[j - 4];
            am = fmaf(p, mwj, am);
            ap = fmaf(p, pwj, ap);
          }
        }
        float m = fmaxf(am + mag_b[k], 0.f);
        float ph = 6.28318530718f / (1.f + __expf(-(ap + phase_b[k])));
        float sp_, cp_;
        __sincosf(ph, &sp_, &cp_);
        *(float2*)(nf + ofc) = make_float2(m * cp_, m * sp_);
      }
    }
  }
}

// ---------- K5: gate GEMM, proj computed in-kernel (v15's passing version).
// grid (16 sp, 32 mgg) x 256.
__global__ __launch_bounds__(256, 2) void k_gemm(const float* __restrict__ fftc,
                                                 const float* __restrict__ W_proj,
                                                 const float* __restrict__ b_proj,
                                                 const unsigned short* __restrict__ Bf,
                                                 unsigned short* __restrict__ gpart) {
  __shared__ __align__(16) unsigned short As[2][4096];  // [buf][(kf*4+mi)*512 + lane*8]
  const int tid = threadIdx.x;
  const int sp = blockIdx.x, mgg = blockIdx.y;
  const int lane = tid & 63, wv = tid >> 6;
  const int q = lane >> 4, l15 = lane & 15;
  const int p0 = (NF_ * sp) >> 4, p1 = (NF_ * (sp + 1)) >> 4;
  const int nsteps = p1 - p0;                 // 16 or 17 (one n per step)
  const int c0 = wv * 2, c1 = c0 + 1;         // LDS chunk = kf*4 + mi
  const int kf = wv >> 1;                     // h-half this wave stages
  const int mi0 = (wv & 1) * 2;
  const int b0 = mgg * 4 + mi0, b1 = b0 + 1;  // global batch rows staged

  // per-thread W_proj slice for its 8 h values (h = kf*32 + q*8 + j)
  float4 w4[8]; float bpv[8];
  const int hb = kf * 32 + q * 8;
#pragma unroll
  for (int j = 0; j < 8; ++j) {
    const int h = hb + j;
    w4[j] = make_float4(W_proj[h], W_proj[64 + h], W_proj[128 + h], W_proj[192 + h]);
    bpv[j] = b_proj[h];
  }

  const unsigned short* pb = Bf + (size_t)(wv * 5) * FRAGS
                             + (size_t)(p0 * 2) * 512 + lane * 8;

  floatx4 acc[4][5];
#pragma unroll
  for (int mi = 0; mi < 4; ++mi)
#pragma unroll
    for (int nn = 0; nn < 5; ++nn) acc[mi][nn] = (floatx4){0.f, 0.f, 0.f, 0.f};

  float2 z0 = *(const float2*)(fftc + ((b0 * NF_ + p0) * 16 + l15) * 2);
  float2 z1 = *(const float2*)(fftc + ((b1 * NF_ + p0) * 16 + l15) * 2);
  short8 bX[5], bY[5];
#pragma unroll
  for (int nn = 0; nn < 5; ++nn) {
    bX[nn] = *(const short8*)(pb + (size_t)nn * FRAGS);
    bY[nn] = *(const short8*)(pb + (size_t)nn * FRAGS + 512);
  }

  for (int s = 0; s < nsteps; ++s) {
    const int n = p0 + s;
    const float fr = (float)n * 0.1953125f;
    float2 zn0, zn1;
    if (s + 1 < nsteps) {
      zn0 = *(const float2*)(fftc + ((b0 * NF_ + n + 1) * 16 + l15) * 2);
      zn1 = *(const float2*)(fftc + ((b1 * NF_ + n + 1) * 16 + l15) * 2);
    }
    unsigned short* dst = &As[s & 1][0];
    {
      float d = z0.x * z0.x + z0.y * z0.y;
      float ir = d > 0.f ? rsqrtf(d) : 0.f;
      float mag = d * ir, sn = z0.y * ir;
      float cs = d > 0.f ? z0.x * ir : 1.f;
      unsigned int w[4];
#pragma unroll
      for (int j = 0; j < 8; ++j) {
        float p = fmaf(mag, w4[j].x, fmaf(sn, w4[j].y, fmaf(cs, w4[j].z,
                  fmaf(fr, w4[j].w, bpv[j]))));
        p = fmaxf(p, 0.f);
        unsigned int pb16 = f2bf(p);
        if (j & 1) w[j >> 1] |= pb16 << 16; else w[j >> 1] = pb16;
      }
      *(uint4*)(dst + c0 * 512 + lane * 8) = make_uint4(w[0], w[1], w[2], w[3]);
    }
    {
      float d = z1.x * z1.x + z1.y * z1.y;
      float ir = d > 0.f ? rsqrtf(d) : 0.f;
      float mag = d * ir, sn = z1.y * ir;
      float cs = d > 0.f ? z1.x * ir : 1.f;
      unsigned int w[4];
#pragma unroll
      for (int j = 0; j < 8; ++j) {
        float p = fmaf(mag, w4[j].x, fmaf(sn, w4[j].y, fmaf(cs, w4[j].z,
                  fmaf(fr, w4[j].w, bpv[j]))));
        p = fmaxf(p, 0.f);
        unsigned int pb16 = f2bf(p);
        if (j & 1) w[j >> 1] |= pb16 << 16; else w[j >> 1] = pb16;
      }
      *(uint4*)(dst + c1 * 512 + lane * 8) = make_uint4(w[0], w[1], w[2], w[3]);
    }
    z0 = zn0; z1 = zn1;
    __builtin_amdgcn_sched_barrier(0);
    asm volatile("s_waitcnt lgkmcnt(0)" ::: "memory");
    __builtin_amdgcn_s_barrier();
    __builtin_amdgcn_sched_barrier(0);
    const unsigned short* rb = &As[s & 1][0];
    {
      short8 a0 = *(const short8*)(rb + 0 * 512 + lane * 8);
      short8 a1 = *(const short8*)(rb + 1 * 512 + lane * 8);
      short8 a2 = *(const short8*)(rb + 2 * 512 + lane * 8);
      short8 a3 = *(const short8*)(rb + 3 * 512 + lane * 8);
#pragma unroll
      for (int nn = 0; nn < 5; ++nn) {
        acc[0][nn] = __builtin_amdgcn_mfma_f32_16x16x32_bf16(a0, bX[nn], acc[0][nn], 0, 0, 0);
        acc[1][nn] = __builtin_amdgcn_mfma_f32_16x16x32_bf16(a1, bX[nn], acc[1][nn], 0, 0, 0);
        acc[2][nn] = __builtin_amdgcn_mfma_f32_16x16x32_bf16(a2, bX[nn], acc[2][nn], 0, 0, 0);
        acc[3][nn] = __builtin_amdgcn_mfma_f32_16x16x32_bf16(a3, bX[nn], acc[3][nn], 0, 0, 0);
      }
      if (s + 1 < nsteps) {
#pragma unroll
        for (int nn = 0; nn < 5; ++nn)
          bX[nn] = *(const short8*)(pb + (size_t)nn * FRAGS + 1024);
      }
    }
    {
      short8 a0 = *(const short8*)(rb + 4 * 512 + lane * 8);
      short8 a1 = *(const short8*)(rb + 5 * 512 + lane * 8);
      short8 a2 = *(const short8*)(rb + 6 * 512 + lane * 8);
      short8 a3 = *(const short8*)(rb + 7 * 512 + lane * 8);
#pragma unroll
      for (int nn = 0; nn < 5; ++nn) {
        acc[0][nn] = __builtin_amdgcn_mfma_f32_16x16x32_bf16(a0, bY[nn], acc[0][nn], 0, 0, 0);
        acc[1][nn] = __builtin_amdgcn_mfma_f32_16x16x32_bf16(a1, bY[nn], acc[1][nn], 0, 0, 0);
        acc[2][nn] = __builtin_amdgcn_mfma_f32_16x16x32_bf16(a2, bY[nn], acc[2][nn], 0, 0, 0);
        acc[3][nn] = __builtin_amdgcn_mfma_f32_16x16x32_bf16(a3, bY[nn], acc[3][nn], 0, 0, 0);
      }
      if (s + 1 < nsteps) {
#pragma unroll
        for (int nn = 0; nn < 5; ++nn)
          bY[nn] = *(const short8*)(pb + (size_t)nn * FRAGS + 1536);
        pb += 1024;
      }
    }
  }

  // fragment-major partial store: coalesced 8B/lane.
#pragma unroll
  for (int mi = 0; mi < 4; ++mi)
#pragma unroll
    for (int nn = 0; nn < 5; ++nn) {
      unsigned int lo = f2bf(acc[mi][nn][0]) | (f2bf(acc[mi][nn][1]) << 16);
      unsigned int hi = f2bf(acc[mi][nn][2]) | (f2bf(acc[mi][nn][3]) << 16);
      *(uint2*)(gpart + ((((size_t)sp * 128 + mgg * 4 + mi) * 20) + wv * 5 + nn) * 256
                + lane * 4) = make_uint2(lo, hi);
    }
}

// ---------- K6: irfft GEMM + fused split-K w-reduction (depth SPK=16).
// grid (2,128) x 512 thr. out = LN(ITWf x WF^T + x).
__global__ __launch_bounds__(512) void k_recong(const float* __restrict__ fftc,
                                                const float* __restrict__ nfb,
                                                const unsigned short* __restrict__ gpart,
                                                const float* __restrict__ b_gate,
                                                const unsigned short* __restrict__ ITWf,
                                                const float* __restrict__ x,
                                                const float* __restrict__ ln_g,
                                                const float* __restrict__ ln_b,
                                                float* __restrict__ out) {
  __shared__ __align__(16) unsigned short WFs[16 * 576];
  __shared__ float wls[16 * 257];
  const int tid = threadIdx.x, th = blockIdx.x, bb = blockIdx.y;
  // fused w-reduction: sum SPK partials from gpart fragment layout.
  const unsigned short* gpb = gpart + (size_t)bb * 5120;   // mfrag = bb
  for (int t = tid; t < 1088; t += 512) {
    const int n = ((t >> 6) << 4) + (t & 15);
    if (n < NF_) {
      const int quad = (t >> 4) & 3;
      const float bg = b_gate[n];
      float g0 = bg, g1 = bg, g2 = bg, g3 = bg;
#pragma unroll
      for (int s2 = 0; s2 < SPK; ++s2) {
        uint2 v = *(const uint2*)(gpb + (size_t)s2 * 655360 + (size_t)t * 4);
        g0 += bf2f(v.x & 0xFFFFu); g1 += bf2f(v.x >> 16);
        g2 += bf2f(v.y & 0xFFFFu); g3 += bf2f(v.y >> 16);
      }
      float gv[4] = {g0, g1, g2, g3};
#pragma unroll
      for (int r = 0; r < 4; ++r) {
        float g = gv[r];
        float sg = 1.f / (1.f + __expf(-g));
        float gs = g * sg;
        wls[(quad * 4 + r) * 257 + n] = 1.f / (1.f + __expf(-gs));
      }
    }
  }
  __syncthreads();
#pragma unroll
  for (int it = 0; it < 17; ++it) {
    int e = it * 512 + tid;        // < 8704 = 16*544
    int f = e & 15, row = e >> 4;
    float val = 0.f;
    if (row < 514) {
      int k = row >> 1, ri = row & 1;
      int base = ((bb * NF_ + k) * 16 + f) * 2 + ri;
      float fz = fftc[base], nz = nfb[base];
      float wv = wls[f * 257 + k];
      val = fz + wv * (nz - fz);
    }
    WFs[f * 576 + (((row >> 3) ^ (f & 7)) * 8) + (row & 7)] = (unsigned short)f2bf(val);
  }
  __syncthreads();
  const int lane = tid & 63, wave = tid >> 6;   // 8 waves x 2 tiles
  const int l15 = lane & 15, quad = lane >> 4;
  const float gg = ln_g[l15], gb = ln_b[l15];
  floatx4 acc[2];
  acc[0] = (floatx4){0.f, 0.f, 0.f, 0.f};
  acc[1] = (floatx4){0.f, 0.f, 0.f, 0.f};
  const int tg0 = th * 16 + wave, tg1 = tg0 + 8;
#pragma unroll
  for (int ks = 0; ks < 17; ++ks) {
    short8 bf = *(const short8*)&WFs[l15 * 576 + (((ks * 4 + quad) ^ (l15 & 7)) * 8)];
    short8 af0 = *(const short8*)(ITWf + tg0 * 8704 + ks * 512 + quad * 128 + l15 * 8);
    short8 af1 = *(const short8*)(ITWf + tg1 * 8704 + ks * 512 + quad * 128 + l15 * 8);
    acc[0] = __builtin_amdgcn_mfma_f32_16x16x32_bf16(af0, bf, acc[0], 0, 0, 0);
    acc[1] = __builtin_amdgcn_mfma_f32_16x16x32_bf16(af1, bf, acc[1], 0, 0, 0);
  }
#pragma unroll
  for (int i = 0; i < 2; ++i) {
    const int tg = (i == 0) ? tg0 : tg1;
#pragma unroll
    for (int r = 0; r < 4; ++r) {
      const int t = tg * 16 + quad * 4 + r;
      float y = acc[i][r] + x[(bb * 512 + t) * 16 + l15];
      float s1 = y, s2 = y * y;
#pragma unroll
      for (int m = 1; m < 16; m <<= 1) {
        s1 += __shfl_xor(s1, m);
        s2 += __shfl_xor(s2, m);
      }
      float mu = s1 * 0.0625f;
      float var = s2 * 0.0625f - mu * mu;
      float rs = rsqrtf(var + 1e-5f);
      out[(bb * 512 + t) * 16 + l15] = (y - mu) * rs * gg + gb;
    }
  }
}

extern "C" void kernel_launch(void* const* d_in, const int* in_sizes, int n_in,
                              void* d_out, int out_size, void* d_ws, size_t ws_size,
                              hipStream_t stream) {
  const float* x = (const float*)d_in[0];
  const float* W_proj = (const float*)d_in[1];
  const float* b_proj = (const float*)d_in[2];
  const float* W_gate = (const float*)d_in[3];
  const float* b_gate = (const float*)d_in[4];
  const float* mag_w = (const float*)d_in[5];
  const float* mag_b = (const float*)d_in[6];
  const float* phase_w = (const float*)d_in[7];
  const float* phase_b = (const float*)d_in[8];
  const float* ln_g = (const float*)d_in[9];
  const float* ln_b = (const float*)d_in[10];
  float* out = (float*)d_out;
  float* ws = (float*)d_ws;

  // workspace (float slots)
  float* fftc = ws;                                          // 1,052,672 f
  float* nfb = ws + 1052672;                                 // 1,052,672 f
  float* csd = ws + 2631680;                                 //    65,792 f
  unsigned short* Bfrag = (unsigned short*)(ws + 2697472);   //  5,263,360 sh (10.5 MB)
  unsigned short* gpart = (unsigned short*)(ws + 5329152);   // 10,485,760 sh (21.0 MB)
  unsigned short* TWf = (unsigned short*)(ws + 10572032);    //    278,528 sh
  unsigned short* ITWf = (unsigned short*)(ws + 10711296);   //    278,528 sh

  hipLaunchKernelGGL(k_prep, dim3(2970), dim3(256), 0, stream,
                     x, W_gate, csd, Bfrag, TWf, ITWf);
  hipLaunchKernelGGL(k_spec, dim3(2, 128), dim3(512), 0, stream, x, TWf, csd,
                     W_proj, b_proj, mag_w, mag_b, phase_w, phase_b, fftc, nfb);
  hipLaunchKernelGGL(k_gemm, dim3(16, 32), dim3(256), 0, stream, fftc, W_proj,
                     b_proj, Bfrag, gpart);
  hipLaunchKernelGGL(k_recong, dim3(2, 128), dim3(512), 0, stream, fftc, nfb, gpart,
                     b_gate, ITWf, x, ln_g, ln_b, out);
}